// Round 13
// baseline (615.385 us; speedup 1.0000x reference)
//
#include <hip/hip_runtime.h>
#include <hip/hip_bf16.h>

#define NN      262144    // N = B*WIN_IN*NODES
#define EDGES   2097152
#define FEATD   16
#define HIDD    64
#define LSTMH   32
#define BATCH   64
#define WIN     32
#define WOUT    8
#define NCLS    10
#define ROWD    2048      // NODES*FEAT = B*WIN (both 2048)
#define KCHUNKS 8

#define NB      2048      // source buckets: r >> 7
#define SH      8         // shards to cut counter contention
#define CAP     256       // pow2: slot = sb*256+pos ; Poisson(128)+11 sigma
#define SLOTS   (NB * SH * CAP)   // 4.19M

// ---- degree: deg[col] += 1 (float, fire-and-forget) ----
__global__ void k_deg(const int* __restrict__ ei, float* __restrict__ deg) {
    int stride = gridDim.x * blockDim.x;
    for (int e = blockIdx.x * blockDim.x + threadIdx.x; e < EDGES; e += stride)
        atomicAdd(&deg[ei[EDGES + e]], 1.0f);
}

// ---- dinv = rsqrt(deg+1) in place ----
__global__ void k_dinv(float* __restrict__ d) {
    int i = blockIdx.x * blockDim.x + threadIdx.x;
    if (i < NN) d[i] = rsqrtf(d[i] + 1.0f);
}

// ---- bucketize by SOURCE: bdata[((r>>7)*SH+s)*256+pos] = (c<<7)|(r&127) ----
// Gathers of xs[r] then happen dest... source-compactly; atomic writes are
// order-invariant (per-op memory-side traffic), so sort key serves fetch only.
__global__ void k_bucketize(const int* __restrict__ ei, int* __restrict__ bcnt,
                            int* __restrict__ bdata) {
    int s = blockIdx.x & (SH - 1);
    int stride = gridDim.x * blockDim.x;
    for (int e = blockIdx.x * blockDim.x + threadIdx.x; e < EDGES; e += stride) {
        int r = ei[e];
        int c = ei[EDGES + e];
        int sb = (r >> 7) * SH + s;
        int pos = atomicAdd(&bcnt[sb], 1);
        if (pos < CAP) bdata[(size_t)sb * CAP + pos] = (c << 7) | (r & 127);
    }
}

// ---- pre-scale: xs[n][f] = x[n][f] * dinv[n] ----
__global__ void k_scale(const float* __restrict__ x, const float* __restrict__ dinv,
                        float* __restrict__ xs) {
    int i = blockIdx.x * blockDim.x + threadIdx.x;   // float4 index
    if (i >= NN * 4) return;
    float d = dinv[i >> 2];
    float4 v = ((const float4*)x)[i];
    v.x *= d; v.y *= d; v.z *= d; v.w *= d;
    ((float4*)xs)[i] = v;
}

// ---- flat aggregation over SOURCE-sorted slots, XCD-swizzled ----
// agg[c][f] += xs[r][f]; 16 lanes/edge; fire-and-forget global atomics.
// Swizzle gives each XCD a disjoint contiguous bucket range -> source rows
// stay resident in that XCD's private L2 (~64KB hot window).
__global__ void __launch_bounds__(256)
k_agg(const int* __restrict__ bcnt, const int* __restrict__ bdata,
      const float* __restrict__ xs, float* __restrict__ agg) {
    int bid = (blockIdx.x & 7) * (8192 / 8) + (blockIdx.x >> 3);   // XCD-chunk swizzle
    int stride = gridDim.x * blockDim.x;
    const long total = (long)SLOTS * FEATD;   // 67.1M lanes
    for (long t = (long)bid * blockDim.x + threadIdx.x; t < total; t += stride) {
        int slot = (int)(t >> 4);
        int f = (int)t & 15;
        int sb = slot >> 8;                  // CAP=256
        int pos = slot & 255;
        if (pos >= bcnt[sb]) continue;       // padded slot
        int w = bdata[slot];
        int r = ((sb >> 3) << 7) | (w & 127);
        int c = w >> 7;
        atomicAdd(&agg[(size_t)c * FEATD + f], xs[(size_t)r * FEATD + f]);
    }
}

// ---- fused MLP (+combine1): in = (agg1+xs)*dinv ; hid = relu(in@W1+b1) ;
//      t2s = (hid@W2)*dinv  -- written in place over xs (row-local) ----
__global__ void k_gcnmlp(const float* __restrict__ agg1, const float* __restrict__ xs,
                         const float* __restrict__ dinv,
                         const float* __restrict__ W1, const float* __restrict__ b1,
                         const float* __restrict__ W2, float* __restrict__ t2) {
    __shared__ float sW1[FEATD * HIDD];
    __shared__ float sW2[HIDD * FEATD];
    __shared__ float sb1[HIDD];
    for (int l = threadIdx.x; l < FEATD * HIDD; l += blockDim.x) {
        sW1[l] = W1[l];
        sW2[l] = W2[l];
    }
    if (threadIdx.x < HIDD) sb1[threadIdx.x] = b1[threadIdx.x];
    __syncthreads();
    int n = blockIdx.x * blockDim.x + threadIdx.x;
    if (n >= NN) return;
    float dn = dinv[n];
    float in[FEATD];
    const float4* aa = (const float4*)(agg1 + (size_t)n * FEATD);
    const float4* ss = (const float4*)(xs + (size_t)n * FEATD);
#pragma unroll
    for (int q = 0; q < 4; q++) {
        float4 a = aa[q], s = ss[q];
        in[q * 4 + 0] = (a.x + s.x) * dn;
        in[q * 4 + 1] = (a.y + s.y) * dn;
        in[q * 4 + 2] = (a.z + s.z) * dn;
        in[q * 4 + 3] = (a.w + s.w) * dn;
    }
    float out[FEATD];
#pragma unroll
    for (int c = 0; c < FEATD; c++) out[c] = 0.f;
#pragma unroll 8
    for (int j = 0; j < HIDD; j++) {
        float h = sb1[j];
#pragma unroll
        for (int f = 0; f < FEATD; f++) h += in[f] * sW1[f * HIDD + j];
        h = fmaxf(h, 0.f);
#pragma unroll
        for (int c = 0; c < FEATD; c++) out[c] += h * sW2[j * FEATD + c];
    }
    float4* o = (float4*)(t2 + (size_t)n * FEATD);
    o[0] = make_float4(out[0] * dn, out[1] * dn, out[2] * dn, out[3] * dn);
    o[1] = make_float4(out[4] * dn, out[5] * dn, out[6] * dn, out[7] * dn);
    o[2] = make_float4(out[8] * dn, out[9] * dn, out[10] * dn, out[11] * dn);
    o[3] = make_float4(out[12] * dn, out[13] * dn, out[14] * dn, out[15] * dn);
}

// ---- LSTM input GEMM, fused combine2: A = h2 = relu((agg2+t2s)*dinv + b2) ----
#define KT 32
__global__ void k_gemmA(const float* __restrict__ agg2, const float* __restrict__ t2s,
                        const float* __restrict__ dinv, const float* __restrict__ b2,
                        const float* __restrict__ Wih, float* __restrict__ gxp) {
    __shared__ float As[64][KT + 1];
    __shared__ float Bs[128][KT + 1];
    __shared__ float sb2[16];
    int tid = threadIdx.x;
    int tx = tid & 15, ty = tid >> 4;
    if (tid < 16) sb2[tid] = b2[tid];
    __syncthreads();
    float acc[4][8];
#pragma unroll
    for (int i = 0; i < 4; i++)
#pragma unroll
        for (int j = 0; j < 8; j++) acc[i][j] = 0.f;
    int row0 = blockIdx.x * 64;
    int k0 = blockIdx.y * (ROWD / KCHUNKS);
    for (int kk = 0; kk < ROWD / KCHUNKS; kk += KT) {
        for (int l = tid; l < 64 * KT / 4; l += 256) {
            int rr = l >> 3;
            int cc = (l & 7) * 4;
            int col = k0 + kk + cc;
            int flat = (row0 + rr) * ROWD + col;
            float4 a = *(const float4*)&agg2[flat];
            float4 s = *(const float4*)&t2s[flat];
            float d = dinv[flat >> 4];
            int fb = col & 15;
            As[rr][cc + 0] = fmaxf((a.x + s.x) * d + sb2[fb + 0], 0.f);
            As[rr][cc + 1] = fmaxf((a.y + s.y) * d + sb2[fb + 1], 0.f);
            As[rr][cc + 2] = fmaxf((a.z + s.z) * d + sb2[fb + 2], 0.f);
            As[rr][cc + 3] = fmaxf((a.w + s.w) * d + sb2[fb + 3], 0.f);
        }
        for (int l = tid; l < 128 * KT / 4; l += 256) {
            int rr = l >> 3;
            int cc = (l & 7) * 4;
            float4 v = *(const float4*)&Wih[(size_t)rr * ROWD + k0 + kk + cc];
            Bs[rr][cc + 0] = v.x; Bs[rr][cc + 1] = v.y; Bs[rr][cc + 2] = v.z; Bs[rr][cc + 3] = v.w;
        }
        __syncthreads();
#pragma unroll
        for (int k = 0; k < KT; k++) {
            float a[4], bb[8];
#pragma unroll
            for (int i = 0; i < 4; i++) a[i] = As[ty * 4 + i][k];
#pragma unroll
            for (int j = 0; j < 8; j++) bb[j] = Bs[tx * 8 + j][k];
#pragma unroll
            for (int i = 0; i < 4; i++)
#pragma unroll
                for (int j = 0; j < 8; j++) acc[i][j] += a[i] * bb[j];
        }
        __syncthreads();
    }
    float* outp = gxp + (size_t)blockIdx.y * (ROWD * 128);
#pragma unroll
    for (int i = 0; i < 4; i++)
#pragma unroll
        for (int j = 0; j < 8; j++)
            outp[(size_t)(row0 + ty * 4 + i) * 128 + tx * 8 + j] = acc[i][j];
}

// ---- LSTM recurrence: parallel LDS prereduce of gxp, then serial steps ----
__global__ void k_lstm(const float* __restrict__ gxp, const float* __restrict__ Whh,
                       const float* __restrict__ bih, const float* __restrict__ bhh,
                       float* __restrict__ hseq) {
    __shared__ float sWhhT[LSTMH][4 * LSTMH];   // [k][j] = Whh[j][k]
    __shared__ float sgx[WIN][4 * LSTMH];        // 16 KB: pre-summed gate inputs
    __shared__ float sh[LSTMH], sc[LSTMH], sg[4 * LSTMH];
    int b = blockIdx.x, j = threadIdx.x;
    for (int l = j; l < 4 * LSTMH * LSTMH; l += 4 * LSTMH) {
        int r = l >> 5, k = l & 31;
        sWhhT[k][r] = Whh[l];
    }
#pragma unroll
    for (int t = 0; t < WIN; t++) {
        const float* g0 = gxp + (size_t)(b * WIN + t) * 128 + j;
        float s = 0.f;
#pragma unroll
        for (int p = 0; p < KCHUNKS; p++) s += g0[(size_t)p * ROWD * 128];
        sgx[t][j] = s;
    }
    float bias = bih[j] + bhh[j];
    if (j < LSTMH) { sh[j] = 0.f; sc[j] = 0.f; }
    __syncthreads();
    for (int t = 0; t < WIN; t++) {
        float g = bias + sgx[t][j];
#pragma unroll
        for (int k = 0; k < LSTMH; k++) g += sWhhT[k][j] * sh[k];
        sg[j] = g;
        __syncthreads();
        if (j < LSTMH) {
            float ig = sg[j], fg = sg[32 + j], gg = sg[64 + j], og = sg[96 + j];
            float c = sc[j];
            float si = 1.f / (1.f + __expf(-ig));
            float sf = 1.f / (1.f + __expf(-fg));
            float so = 1.f / (1.f + __expf(-og));
            c = sf * c + si * tanhf(gg);
            float h = so * tanhf(c);
            sc[j] = c; sh[j] = h;
            if (t >= WIN - WOUT)
                hseq[(size_t)(b * WOUT + (t - (WIN - WOUT))) * LSTMH + j] = h;
        }
        __syncthreads();
    }
}

// ---- FC head: (512 rows) 32 -> 16 relu -> 10 ----
__global__ void k_fc(const float* __restrict__ hseq, const float* __restrict__ Wfc1,
                     const float* __restrict__ bfc1, const float* __restrict__ Wfc2,
                     const float* __restrict__ bfc2, float* __restrict__ out) {
    __shared__ float sW1[16 * 32], sb1[16], sW2[10 * 16], sb2[10];
    int tid = threadIdx.x;
    for (int l = tid; l < 16 * 32; l += blockDim.x) sW1[l] = Wfc1[l];
    if (tid < 16) sb1[tid] = bfc1[tid];
    for (int l = tid; l < 160; l += blockDim.x) sW2[l] = Wfc2[l];
    if (tid < 10) sb2[tid] = bfc2[tid];
    __syncthreads();
    int r = blockIdx.x * blockDim.x + tid;
    if (r >= BATCH * WOUT) return;
    float h[32];
#pragma unroll
    for (int k = 0; k < 32; k++) h[k] = hseq[(size_t)r * 32 + k];
    float hid[16];
#pragma unroll
    for (int j = 0; j < 16; j++) {
        float v = sb1[j];
#pragma unroll
        for (int k = 0; k < 32; k++) v += sW1[j * 32 + k] * h[k];
        hid[j] = fmaxf(v, 0.f);
    }
#pragma unroll
    for (int c = 0; c < NCLS; c++) {
        float v = sb2[c];
#pragma unroll
        for (int j = 0; j < 16; j++) v += sW2[c * 16 + j] * hid[j];
        out[(size_t)r * NCLS + c] = v;
    }
}

extern "C" void kernel_launch(void* const* d_in, const int* in_sizes, int n_in,
                              void* d_out, int out_size, void* d_ws, size_t ws_size,
                              hipStream_t stream) {
    const float* x    = (const float*)d_in[0];
    const int*   ei   = (const int*)d_in[1];
    const float* W1   = (const float*)d_in[2];
    const float* b1   = (const float*)d_in[3];
    const float* W2   = (const float*)d_in[4];
    const float* b2   = (const float*)d_in[5];
    const float* Wih  = (const float*)d_in[6];
    const float* Whh  = (const float*)d_in[7];
    const float* bih  = (const float*)d_in[8];
    const float* bhh  = (const float*)d_in[9];
    const float* Wfc1 = (const float*)d_in[10];
    const float* bfc1 = (const float*)d_in[11];
    const float* Wfc2 = (const float*)d_in[12];
    const float* bfc2 = (const float*)d_in[13];
    float* out = (float*)d_out;

    float* ws    = (float*)d_ws;
    float* dinv  = ws;                                    // NN floats (1 MB)
    int*   bcnt  = (int*)(dinv + NN);                     // NB*SH ints (64 KB)
    int*   bdata = bcnt + NB * SH;                        // SLOTS ints (16.8 MB)
    float* bufA  = (float*)(bdata + (size_t)SLOTS);       // NN*16 (16 MB): agg1/agg2
    float* bufB  = bufA + (size_t)NN * FEATD;             // NN*16 (16 MB): xs -> t2s
    float* gxp   = (float*)bdata;                         // 8 MB, aliases dead bdata
    float* hseq  = bufB + (size_t)NN * FEATD;             // 16384 floats

    // zero dinv + bcnt (contiguous)
    (void)hipMemsetAsync(dinv, 0, (size_t)(NN + NB * SH) * sizeof(int), stream);
    k_deg<<<2048, 256, 0, stream>>>(ei, dinv);
    k_bucketize<<<2048, 256, 0, stream>>>(ei, bcnt, bdata);
    k_dinv<<<NN / 256, 256, 0, stream>>>(dinv);
    k_scale<<<NN * 4 / 256, 256, 0, stream>>>(x, dinv, bufB);          // xs

    (void)hipMemsetAsync(bufA, 0, (size_t)NN * FEATD * sizeof(float), stream);
    k_agg<<<8192, 256, 0, stream>>>(bcnt, bdata, bufB, bufA);          // agg1
    k_gcnmlp<<<NN / 256, 256, 0, stream>>>(bufA, bufB, dinv, W1, b1, W2, bufB);  // t2s

    (void)hipMemsetAsync(bufA, 0, (size_t)NN * FEATD * sizeof(float), stream);
    k_agg<<<8192, 256, 0, stream>>>(bcnt, bdata, bufB, bufA);          // agg2

    dim3 gg(ROWD / 64, KCHUNKS);
    k_gemmA<<<gg, 256, 0, stream>>>(bufA, bufB, dinv, b2, Wih, gxp);
    k_lstm<<<BATCH, 128, 0, stream>>>(gxp, Whh, bih, bhh, hseq);
    k_fc<<<2, 256, 0, stream>>>(hseq, Wfc1, bfc1, Wfc2, bfc2, out);
}

// Round 15
// 477.811 us; speedup vs baseline: 1.2879x; 1.2879x over previous
//
#include <hip/hip_runtime.h>
#include <hip/hip_bf16.h>

#define NN      262144    // N = B*WIN_IN*NODES
#define EDGES   2097152
#define FEATD   16
#define HIDD    64
#define LSTMH   32
#define BATCH   64
#define WIN     32
#define WOUT    8
#define NCLS    10
#define ROWD    2048      // NODES*FEAT = B*WIN (both 2048)
#define KCHUNKS 8

// ---- degree: deg[col] += 1 (float, fire-and-forget) ----
__global__ void k_deg(const int* __restrict__ ei, float* __restrict__ deg) {
    int stride = gridDim.x * blockDim.x;
    for (int e = blockIdx.x * blockDim.x + threadIdx.x; e < EDGES; e += stride)
        atomicAdd(&deg[ei[EDGES + e]], 1.0f);
}

// ---- dinv = rsqrt(deg+1) in place ----
__global__ void k_dinv(float* __restrict__ d) {
    int i = blockIdx.x * blockDim.x + threadIdx.x;
    if (i < NN) d[i] = rsqrtf(d[i] + 1.0f);
}

// ---- pre-scale: xs[n][f] = x[n][f] * dinv[n] ----
__global__ void k_scale(const float* __restrict__ x, const float* __restrict__ dinv,
                        float* __restrict__ xs) {
    int i = blockIdx.x * blockDim.x + threadIdx.x;   // float4 index
    if (i >= NN * 4) return;
    float d = dinv[i >> 2];
    float4 v = ((const float4*)x)[i];
    v.x *= d; v.y *= d; v.z *= d; v.w *= d;
    ((float4*)xs)[i] = v;
}

// ---- edge aggregation (round-11 proven, atomic-rate floor ~108us):
// thread = (edge, feat); 33.5M independent lanes, no barriers, fire-and-forget
// global atomics; 16 lanes share one edge -> 64B coalesced gather. ----
__global__ void __launch_bounds__(256)
k_agg(const int* __restrict__ ei, const float* __restrict__ xs,
      float* __restrict__ agg) {
    int stride = gridDim.x * blockDim.x;
    const int total = EDGES * FEATD;
    for (int t = blockIdx.x * blockDim.x + threadIdx.x; t < total; t += stride) {
        int e = t >> 4;
        int f = t & 15;
        int r = ei[e];
        int c = ei[EDGES + e];
        atomicAdd(&agg[(size_t)c * FEATD + f], xs[(size_t)r * FEATD + f]);
    }
}

// ---- fused MLP (+combine1): in = (agg1+xs)*dinv ; hid = relu(in@W1+b1) ;
//      t2s = (hid@W2)*dinv  -- written in place over xs (row-local) ----
__global__ void k_gcnmlp(const float* __restrict__ agg1, const float* __restrict__ xs,
                         const float* __restrict__ dinv,
                         const float* __restrict__ W1, const float* __restrict__ b1,
                         const float* __restrict__ W2, float* __restrict__ t2) {
    __shared__ float sW1[FEATD * HIDD];
    __shared__ float sW2[HIDD * FEATD];
    __shared__ float sb1[HIDD];
    for (int l = threadIdx.x; l < FEATD * HIDD; l += blockDim.x) {
        sW1[l] = W1[l];
        sW2[l] = W2[l];
    }
    if (threadIdx.x < HIDD) sb1[threadIdx.x] = b1[threadIdx.x];
    __syncthreads();
    int n = blockIdx.x * blockDim.x + threadIdx.x;
    if (n >= NN) return;
    float dn = dinv[n];
    float in[FEATD];
    const float4* aa = (const float4*)(agg1 + (size_t)n * FEATD);
    const float4* ss = (const float4*)(xs + (size_t)n * FEATD);
#pragma unroll
    for (int q = 0; q < 4; q++) {
        float4 a = aa[q], s = ss[q];
        in[q * 4 + 0] = (a.x + s.x) * dn;
        in[q * 4 + 1] = (a.y + s.y) * dn;
        in[q * 4 + 2] = (a.z + s.z) * dn;
        in[q * 4 + 3] = (a.w + s.w) * dn;
    }
    float out[FEATD];
#pragma unroll
    for (int c = 0; c < FEATD; c++) out[c] = 0.f;
#pragma unroll 8
    for (int j = 0; j < HIDD; j++) {
        float h = sb1[j];
#pragma unroll
        for (int f = 0; f < FEATD; f++) h += in[f] * sW1[f * HIDD + j];
        h = fmaxf(h, 0.f);
#pragma unroll
        for (int c = 0; c < FEATD; c++) out[c] += h * sW2[j * FEATD + c];
    }
    float4* o = (float4*)(t2 + (size_t)n * FEATD);
    o[0] = make_float4(out[0] * dn, out[1] * dn, out[2] * dn, out[3] * dn);
    o[1] = make_float4(out[4] * dn, out[5] * dn, out[6] * dn, out[7] * dn);
    o[2] = make_float4(out[8] * dn, out[9] * dn, out[10] * dn, out[11] * dn);
    o[3] = make_float4(out[12] * dn, out[13] * dn, out[14] * dn, out[15] * dn);
}

// ---- LSTM input GEMM, fused combine2: A = h2 = relu((agg2+t2s)*dinv + b2) ----
#define KT 32
__global__ void k_gemmA(const float* __restrict__ agg2, const float* __restrict__ t2s,
                        const float* __restrict__ dinv, const float* __restrict__ b2,
                        const float* __restrict__ Wih, float* __restrict__ gxp) {
    __shared__ float As[64][KT + 1];
    __shared__ float Bs[128][KT + 1];
    __shared__ float sb2[16];
    int tid = threadIdx.x;
    int tx = tid & 15, ty = tid >> 4;
    if (tid < 16) sb2[tid] = b2[tid];
    __syncthreads();
    float acc[4][8];
#pragma unroll
    for (int i = 0; i < 4; i++)
#pragma unroll
        for (int j = 0; j < 8; j++) acc[i][j] = 0.f;
    int row0 = blockIdx.x * 64;
    int k0 = blockIdx.y * (ROWD / KCHUNKS);
    for (int kk = 0; kk < ROWD / KCHUNKS; kk += KT) {
        for (int l = tid; l < 64 * KT / 4; l += 256) {
            int rr = l >> 3;
            int cc = (l & 7) * 4;
            int col = k0 + kk + cc;
            int flat = (row0 + rr) * ROWD + col;
            float4 a = *(const float4*)&agg2[flat];
            float4 s = *(const float4*)&t2s[flat];
            float d = dinv[flat >> 4];
            int fb = col & 15;
            As[rr][cc + 0] = fmaxf((a.x + s.x) * d + sb2[fb + 0], 0.f);
            As[rr][cc + 1] = fmaxf((a.y + s.y) * d + sb2[fb + 1], 0.f);
            As[rr][cc + 2] = fmaxf((a.z + s.z) * d + sb2[fb + 2], 0.f);
            As[rr][cc + 3] = fmaxf((a.w + s.w) * d + sb2[fb + 3], 0.f);
        }
        for (int l = tid; l < 128 * KT / 4; l += 256) {
            int rr = l >> 3;
            int cc = (l & 7) * 4;
            float4 v = *(const float4*)&Wih[(size_t)rr * ROWD + k0 + kk + cc];
            Bs[rr][cc + 0] = v.x; Bs[rr][cc + 1] = v.y; Bs[rr][cc + 2] = v.z; Bs[rr][cc + 3] = v.w;
        }
        __syncthreads();
#pragma unroll
        for (int k = 0; k < KT; k++) {
            float a[4], bb[8];
#pragma unroll
            for (int i = 0; i < 4; i++) a[i] = As[ty * 4 + i][k];
#pragma unroll
            for (int j = 0; j < 8; j++) bb[j] = Bs[tx * 8 + j][k];
#pragma unroll
            for (int i = 0; i < 4; i++)
#pragma unroll
                for (int j = 0; j < 8; j++) acc[i][j] += a[i] * bb[j];
        }
        __syncthreads();
    }
    float* outp = gxp + (size_t)blockIdx.y * (ROWD * 128);
#pragma unroll
    for (int i = 0; i < 4; i++)
#pragma unroll
        for (int j = 0; j < 8; j++)
            outp[(size_t)(row0 + ty * 4 + i) * 128 + tx * 8 + j] = acc[i][j];
}

// ---- LSTM recurrence: parallel LDS prereduce of gxp, then serial steps ----
__global__ void k_lstm(const float* __restrict__ gxp, const float* __restrict__ Whh,
                       const float* __restrict__ bih, const float* __restrict__ bhh,
                       float* __restrict__ hseq) {
    __shared__ float sWhhT[LSTMH][4 * LSTMH];   // [k][j] = Whh[j][k]
    __shared__ float sgx[WIN][4 * LSTMH];        // 16 KB: pre-summed gate inputs
    __shared__ float sh[LSTMH], sc[LSTMH], sg[4 * LSTMH];
    int b = blockIdx.x, j = threadIdx.x;
    for (int l = j; l < 4 * LSTMH * LSTMH; l += 4 * LSTMH) {
        int r = l >> 5, k = l & 31;
        sWhhT[k][r] = Whh[l];
    }
#pragma unroll
    for (int t = 0; t < WIN; t++) {
        const float* g0 = gxp + (size_t)(b * WIN + t) * 128 + j;
        float s = 0.f;
#pragma unroll
        for (int p = 0; p < KCHUNKS; p++) s += g0[(size_t)p * ROWD * 128];
        sgx[t][j] = s;
    }
    float bias = bih[j] + bhh[j];
    if (j < LSTMH) { sh[j] = 0.f; sc[j] = 0.f; }
    __syncthreads();
    for (int t = 0; t < WIN; t++) {
        float g = bias + sgx[t][j];
#pragma unroll
        for (int k = 0; k < LSTMH; k++) g += sWhhT[k][j] * sh[k];
        sg[j] = g;
        __syncthreads();
        if (j < LSTMH) {
            float ig = sg[j], fg = sg[32 + j], gg = sg[64 + j], og = sg[96 + j];
            float c = sc[j];
            float si = 1.f / (1.f + __expf(-ig));
            float sf = 1.f / (1.f + __expf(-fg));
            float so = 1.f / (1.f + __expf(-og));
            c = sf * c + si * tanhf(gg);
            float h = so * tanhf(c);
            sc[j] = c; sh[j] = h;
            if (t >= WIN - WOUT)
                hseq[(size_t)(b * WOUT + (t - (WIN - WOUT))) * LSTMH + j] = h;
        }
        __syncthreads();
    }
}

// ---- FC head: (512 rows) 32 -> 16 relu -> 10 ----
__global__ void k_fc(const float* __restrict__ hseq, const float* __restrict__ Wfc1,
                     const float* __restrict__ bfc1, const float* __restrict__ Wfc2,
                     const float* __restrict__ bfc2, float* __restrict__ out) {
    __shared__ float sW1[16 * 32], sb1[16], sW2[10 * 16], sb2[10];
    int tid = threadIdx.x;
    for (int l = tid; l < 16 * 32; l += blockDim.x) sW1[l] = Wfc1[l];
    if (tid < 16) sb1[tid] = bfc1[tid];
    for (int l = tid; l < 160; l += blockDim.x) sW2[l] = Wfc2[l];
    if (tid < 10) sb2[tid] = bfc2[tid];
    __syncthreads();
    int r = blockIdx.x * blockDim.x + tid;
    if (r >= BATCH * WOUT) return;
    float h[32];
#pragma unroll
    for (int k = 0; k < 32; k++) h[k] = hseq[(size_t)r * 32 + k];
    float hid[16];
#pragma unroll
    for (int j = 0; j < 16; j++) {
        float v = sb1[j];
#pragma unroll
        for (int k = 0; k < 32; k++) v += sW1[j * 32 + k] * h[k];
        hid[j] = fmaxf(v, 0.f);
    }
#pragma unroll
    for (int c = 0; c < NCLS; c++) {
        float v = sb2[c];
#pragma unroll
        for (int j = 0; j < 16; j++) v += sW2[c * 16 + j] * hid[j];
        out[(size_t)r * NCLS + c] = v;
    }
}

extern "C" void kernel_launch(void* const* d_in, const int* in_sizes, int n_in,
                              void* d_out, int out_size, void* d_ws, size_t ws_size,
                              hipStream_t stream) {
    const float* x    = (const float*)d_in[0];
    const int*   ei   = (const int*)d_in[1];
    const float* W1   = (const float*)d_in[2];
    const float* b1   = (const float*)d_in[3];
    const float* W2   = (const float*)d_in[4];
    const float* b2   = (const float*)d_in[5];
    const float* Wih  = (const float*)d_in[6];
    const float* Whh  = (const float*)d_in[7];
    const float* bih  = (const float*)d_in[8];
    const float* bhh  = (const float*)d_in[9];
    const float* Wfc1 = (const float*)d_in[10];
    const float* bfc1 = (const float*)d_in[11];
    const float* Wfc2 = (const float*)d_in[12];
    const float* bfc2 = (const float*)d_in[13];
    float* out = (float*)d_out;

    float* ws   = (float*)d_ws;
    float* dinv = ws;                                   // NN floats (1 MB)
    float* bufA = dinv + NN;                            // NN*16 (16 MB): agg1/agg2
    float* bufB = bufA + (size_t)NN * FEATD;            // NN*16 (16 MB): xs -> t2s
    float* gxp  = bufB + (size_t)NN * FEATD;            // 8*2048*128 (8 MB)
    float* hseq = gxp + (size_t)KCHUNKS * ROWD * 128;   // 16384 floats

    // zero dinv + bufA in one contiguous memset (dinv used as float deg)
    (void)hipMemsetAsync(dinv, 0, (size_t)(NN + NN * FEATD) * sizeof(float), stream);
    k_deg<<<2048, 256, 0, stream>>>(ei, dinv);
    k_dinv<<<NN / 256, 256, 0, stream>>>(dinv);
    k_scale<<<NN * 4 / 256, 256, 0, stream>>>(x, dinv, bufB);          // xs

    k_agg<<<8192, 256, 0, stream>>>(ei, bufB, bufA);                   // agg1
    k_gcnmlp<<<NN / 256, 256, 0, stream>>>(bufA, bufB, dinv, W1, b1, W2, bufB);  // t2s

    (void)hipMemsetAsync(bufA, 0, (size_t)NN * FEATD * sizeof(float), stream);
    k_agg<<<8192, 256, 0, stream>>>(ei, bufB, bufA);                   // agg2

    dim3 gg(ROWD / 64, KCHUNKS);
    k_gemmA<<<gg, 256, 0, stream>>>(bufA, bufB, dinv, b2, Wih, gxp);
    k_lstm<<<BATCH, 128, 0, stream>>>(gxp, Whh, bih, bhh, hseq);
    k_fc<<<2, 256, 0, stream>>>(hseq, Wfc1, bfc1, Wfc2, bfc2, out);
}

// Round 16
// 461.233 us; speedup vs baseline: 1.3342x; 1.0359x over previous
//
#include <hip/hip_runtime.h>
#include <hip/hip_fp16.h>

#define NN      262144    // N = B*WIN_IN*NODES
#define EDGES   2097152
#define FEATD   16
#define HIDD    64
#define LSTMH   32
#define BATCH   64
#define WIN     32
#define WOUT    8
#define NCLS    10
#define ROWD    2048      // NODES*FEAT = B*WIN (both 2048)
#define KCHUNKS 8

// packed fp16x2 atomic add (native on gfx950; no CAS loop)
__device__ __forceinline__ void pk_atomic_add_f16(void* addr, unsigned int data) {
    asm volatile("global_atomic_pk_add_f16 %0, %1, off" :: "v"(addr), "v"(data) : "memory");
}

// ---- degree: deg[col] += 1 (float, fire-and-forget) ----
__global__ void k_deg(const int* __restrict__ ei, float* __restrict__ deg) {
    int stride = gridDim.x * blockDim.x;
    for (int e = blockIdx.x * blockDim.x + threadIdx.x; e < EDGES; e += stride)
        atomicAdd(&deg[ei[EDGES + e]], 1.0f);
}

// ---- fused dinv+scale: d = rsqrt(deg+1); dinv[n]=d (in place over deg);
// xsH[n][f2] = half2(x*d). 8 lanes per node stay in one wave: the wave's
// read of deg[n] precedes its own write of dinv[n] in program order. ----
__global__ void k_scale(const float* __restrict__ x, float* __restrict__ deg_dinv,
                        __half2* __restrict__ xsH) {
    int i = blockIdx.x * blockDim.x + threadIdx.x;   // half2 lane: NN*8
    if (i >= NN * 8) return;
    int n = i >> 3;
    float d = rsqrtf(deg_dinv[n] + 1.0f);
    float2 v = ((const float2*)x)[i];
    xsH[i] = __floats2half2_rn(v.x * d, v.y * d);
    if ((i & 7) == 0) deg_dinv[n] = d;
}

// ---- edge aggregation, fp16x2 atomics: aggH[c][f2] += xsH[r][f2] ----
// thread = (edge, f2): 16.8M lanes (halved), 8 lanes/edge -> 32B coalesced
// gather + 8 packed atomics/edge (halved op count vs f32).
__global__ void __launch_bounds__(256)
k_agg(const int* __restrict__ ei, const __half2* __restrict__ xsH,
      __half2* __restrict__ aggH) {
    int stride = gridDim.x * blockDim.x;
    const int total = EDGES * 8;
    for (int t = blockIdx.x * blockDim.x + threadIdx.x; t < total; t += stride) {
        int e = t >> 3;
        int f2 = t & 7;
        int r = ei[e];
        int c = ei[EDGES + e];
        unsigned int v = ((const unsigned int*)xsH)[(size_t)r * 8 + f2];
        pk_atomic_add_f16((void*)(aggH + (size_t)c * 8 + f2), v);
    }
}

// ---- fused MLP (+combine1): in = (agg1+xs)*dinv ; hid = relu(in@W1+b1) ;
//      t2s = (hid@W2)*dinv -> fp16, in place over xsH (row-local) ----
__global__ void k_gcnmlp(const __half2* __restrict__ agg1H, __half2* __restrict__ xsH,
                         const float* __restrict__ dinv,
                         const float* __restrict__ W1, const float* __restrict__ b1,
                         const float* __restrict__ W2) {
    __shared__ float sW1[FEATD * HIDD];
    __shared__ float sW2[HIDD * FEATD];
    __shared__ float sb1[HIDD];
    for (int l = threadIdx.x; l < FEATD * HIDD; l += blockDim.x) {
        sW1[l] = W1[l];
        sW2[l] = W2[l];
    }
    if (threadIdx.x < HIDD) sb1[threadIdx.x] = b1[threadIdx.x];
    __syncthreads();
    int n = blockIdx.x * blockDim.x + threadIdx.x;
    if (n >= NN) return;
    float dn = dinv[n];
    union { float4 f4; __half2 h2[4]; } a0, a1, s0, s1;
    a0.f4 = ((const float4*)(agg1H + (size_t)n * 8))[0];
    a1.f4 = ((const float4*)(agg1H + (size_t)n * 8))[1];
    s0.f4 = ((const float4*)(xsH + (size_t)n * 8))[0];
    s1.f4 = ((const float4*)(xsH + (size_t)n * 8))[1];
    float in[FEATD];
#pragma unroll
    for (int q = 0; q < 4; q++) {
        float2 af = __half22float2(a0.h2[q]), sf = __half22float2(s0.h2[q]);
        in[q * 2 + 0] = (af.x + sf.x) * dn;
        in[q * 2 + 1] = (af.y + sf.y) * dn;
        af = __half22float2(a1.h2[q]); sf = __half22float2(s1.h2[q]);
        in[8 + q * 2 + 0] = (af.x + sf.x) * dn;
        in[8 + q * 2 + 1] = (af.y + sf.y) * dn;
    }
    float out[FEATD];
#pragma unroll
    for (int c = 0; c < FEATD; c++) out[c] = 0.f;
#pragma unroll 8
    for (int j = 0; j < HIDD; j++) {
        float h = sb1[j];
#pragma unroll
        for (int f = 0; f < FEATD; f++) h += in[f] * sW1[f * HIDD + j];
        h = fmaxf(h, 0.f);
#pragma unroll
        for (int c = 0; c < FEATD; c++) out[c] += h * sW2[j * FEATD + c];
    }
    union { float4 f4; __half2 h2[4]; } o0, o1;
#pragma unroll
    for (int q = 0; q < 4; q++) {
        o0.h2[q] = __floats2half2_rn(out[q * 2] * dn, out[q * 2 + 1] * dn);
        o1.h2[q] = __floats2half2_rn(out[8 + q * 2] * dn, out[8 + q * 2 + 1] * dn);
    }
    ((float4*)(xsH + (size_t)n * 8))[0] = o0.f4;
    ((float4*)(xsH + (size_t)n * 8))[1] = o1.f4;
}

// ---- LSTM input GEMM, fused combine2: A = h2 = relu((agg2+t2s)*dinv + b2) ----
#define KT 32
__global__ void k_gemmA(const __half2* __restrict__ agg2H, const __half2* __restrict__ t2sH,
                        const float* __restrict__ dinv, const float* __restrict__ b2,
                        const float* __restrict__ Wih, float* __restrict__ gxp) {
    __shared__ float As[64][KT + 1];
    __shared__ float Bs[128][KT + 1];
    __shared__ float sb2[16];
    int tid = threadIdx.x;
    int tx = tid & 15, ty = tid >> 4;
    if (tid < 16) sb2[tid] = b2[tid];
    __syncthreads();
    float acc[4][8];
#pragma unroll
    for (int i = 0; i < 4; i++)
#pragma unroll
        for (int j = 0; j < 8; j++) acc[i][j] = 0.f;
    int row0 = blockIdx.x * 64;
    int k0 = blockIdx.y * (ROWD / KCHUNKS);
    const __half* agg2 = (const __half*)agg2H;
    const __half* t2s = (const __half*)t2sH;
    for (int kk = 0; kk < ROWD / KCHUNKS; kk += KT) {
        {   // A tile: 64 rows x 32 cols, 256 threads x 8 halfs
            int rr = tid >> 2;
            int cc = (tid & 3) * 8;
            int col = k0 + kk + cc;
            size_t flat = (size_t)(row0 + rr) * ROWD + col;
            union { float4 f4; __half2 h2[4]; } a, s;
            a.f4 = *(const float4*)(agg2 + flat);
            s.f4 = *(const float4*)(t2s + flat);
            float d = dinv[flat >> 4];
            int fb = cc & 15;   // (k0+kk)%16==0, so col%16 == cc%16; no wrap over 8
#pragma unroll
            for (int q = 0; q < 4; q++) {
                float2 af = __half22float2(a.h2[q]), sf = __half22float2(s.h2[q]);
                As[rr][cc + q * 2 + 0] = fmaxf((af.x + sf.x) * d + sb2[fb + q * 2 + 0], 0.f);
                As[rr][cc + q * 2 + 1] = fmaxf((af.y + sf.y) * d + sb2[fb + q * 2 + 1], 0.f);
            }
        }
        for (int l = tid; l < 128 * KT / 4; l += 256) {
            int rr = l >> 3;
            int cc = (l & 7) * 4;
            float4 v = *(const float4*)&Wih[(size_t)rr * ROWD + k0 + kk + cc];
            Bs[rr][cc + 0] = v.x; Bs[rr][cc + 1] = v.y; Bs[rr][cc + 2] = v.z; Bs[rr][cc + 3] = v.w;
        }
        __syncthreads();
#pragma unroll
        for (int k = 0; k < KT; k++) {
            float a[4], bb[8];
#pragma unroll
            for (int i = 0; i < 4; i++) a[i] = As[ty * 4 + i][k];
#pragma unroll
            for (int j = 0; j < 8; j++) bb[j] = Bs[tx * 8 + j][k];
#pragma unroll
            for (int i = 0; i < 4; i++)
#pragma unroll
                for (int j = 0; j < 8; j++) acc[i][j] += a[i] * bb[j];
        }
        __syncthreads();
    }
    float* outp = gxp + (size_t)blockIdx.y * (ROWD * 128);
#pragma unroll
    for (int i = 0; i < 4; i++)
#pragma unroll
        for (int j = 0; j < 8; j++)
            outp[(size_t)(row0 + ty * 4 + i) * 128 + tx * 8 + j] = acc[i][j];
}

// ---- LSTM recurrence: parallel LDS prereduce of gxp, then serial steps ----
__global__ void k_lstm(const float* __restrict__ gxp, const float* __restrict__ Whh,
                       const float* __restrict__ bih, const float* __restrict__ bhh,
                       float* __restrict__ hseq) {
    __shared__ float sWhhT[LSTMH][4 * LSTMH];   // [k][j] = Whh[j][k]
    __shared__ float sgx[WIN][4 * LSTMH];        // 16 KB: pre-summed gate inputs
    __shared__ float sh[LSTMH], sc[LSTMH], sg[4 * LSTMH];
    int b = blockIdx.x, j = threadIdx.x;
    for (int l = j; l < 4 * LSTMH * LSTMH; l += 4 * LSTMH) {
        int r = l >> 5, k = l & 31;
        sWhhT[k][r] = Whh[l];
    }
#pragma unroll
    for (int t = 0; t < WIN; t++) {
        const float* g0 = gxp + (size_t)(b * WIN + t) * 128 + j;
        float s = 0.f;
#pragma unroll
        for (int p = 0; p < KCHUNKS; p++) s += g0[(size_t)p * ROWD * 128];
        sgx[t][j] = s;
    }
    float bias = bih[j] + bhh[j];
    if (j < LSTMH) { sh[j] = 0.f; sc[j] = 0.f; }
    __syncthreads();
    for (int t = 0; t < WIN; t++) {
        float g = bias + sgx[t][j];
#pragma unroll
        for (int k = 0; k < LSTMH; k++) g += sWhhT[k][j] * sh[k];
        sg[j] = g;
        __syncthreads();
        if (j < LSTMH) {
            float ig = sg[j], fg = sg[32 + j], gg = sg[64 + j], og = sg[96 + j];
            float c = sc[j];
            float si = 1.f / (1.f + __expf(-ig));
            float sf = 1.f / (1.f + __expf(-fg));
            float so = 1.f / (1.f + __expf(-og));
            c = sf * c + si * tanhf(gg);
            float h = so * tanhf(c);
            sc[j] = c; sh[j] = h;
            if (t >= WIN - WOUT)
                hseq[(size_t)(b * WOUT + (t - (WIN - WOUT))) * LSTMH + j] = h;
        }
        __syncthreads();
    }
}

// ---- FC head: (512 rows) 32 -> 16 relu -> 10 ----
__global__ void k_fc(const float* __restrict__ hseq, const float* __restrict__ Wfc1,
                     const float* __restrict__ bfc1, const float* __restrict__ Wfc2,
                     const float* __restrict__ bfc2, float* __restrict__ out) {
    __shared__ float sW1[16 * 32], sb1[16], sW2[10 * 16], sb2[10];
    int tid = threadIdx.x;
    for (int l = tid; l < 16 * 32; l += blockDim.x) sW1[l] = Wfc1[l];
    if (tid < 16) sb1[tid] = bfc1[tid];
    for (int l = tid; l < 160; l += blockDim.x) sW2[l] = Wfc2[l];
    if (tid < 10) sb2[tid] = bfc2[tid];
    __syncthreads();
    int r = blockIdx.x * blockDim.x + tid;
    if (r >= BATCH * WOUT) return;
    float h[32];
#pragma unroll
    for (int k = 0; k < 32; k++) h[k] = hseq[(size_t)r * 32 + k];
    float hid[16];
#pragma unroll
    for (int j = 0; j < 16; j++) {
        float v = sb1[j];
#pragma unroll
        for (int k = 0; k < 32; k++) v += sW1[j * 32 + k] * h[k];
        hid[j] = fmaxf(v, 0.f);
    }
#pragma unroll
    for (int c = 0; c < NCLS; c++) {
        float v = sb2[c];
#pragma unroll
        for (int j = 0; j < 16; j++) v += sW2[c * 16 + j] * hid[j];
        out[(size_t)r * NCLS + c] = v;
    }
}

extern "C" void kernel_launch(void* const* d_in, const int* in_sizes, int n_in,
                              void* d_out, int out_size, void* d_ws, size_t ws_size,
                              hipStream_t stream) {
    const float* x    = (const float*)d_in[0];
    const int*   ei   = (const int*)d_in[1];
    const float* W1   = (const float*)d_in[2];
    const float* b1   = (const float*)d_in[3];
    const float* W2   = (const float*)d_in[4];
    const float* b2   = (const float*)d_in[5];
    const float* Wih  = (const float*)d_in[6];
    const float* Whh  = (const float*)d_in[7];
    const float* bih  = (const float*)d_in[8];
    const float* bhh  = (const float*)d_in[9];
    const float* Wfc1 = (const float*)d_in[10];
    const float* bfc1 = (const float*)d_in[11];
    const float* Wfc2 = (const float*)d_in[12];
    const float* bfc2 = (const float*)d_in[13];
    float* out = (float*)d_out;

    float*   ws   = (float*)d_ws;
    float*   dinv = ws;                                   // NN f32 (deg -> dinv)
    __half2* aggH = (__half2*)(dinv + NN);                // NN*8 half2 (8 MB)
    __half2* xsH  = aggH + (size_t)NN * 8;                // NN*8 half2 (8 MB): xs -> t2s
    float*   gxp  = (float*)(xsH + (size_t)NN * 8);       // 8*2048*128 f32 (8 MB)
    float*   hseq = gxp + (size_t)KCHUNKS * ROWD * 128;   // 16384 f32

    // zero deg + aggH in one contiguous memset
    (void)hipMemsetAsync(dinv, 0, (size_t)NN * sizeof(float) + (size_t)NN * 16 * sizeof(__half), stream);
    k_deg<<<2048, 256, 0, stream>>>(ei, dinv);
    k_scale<<<NN * 8 / 256, 256, 0, stream>>>(x, dinv, xsH);           // dinv + xsH

    k_agg<<<8192, 256, 0, stream>>>(ei, xsH, aggH);                    // agg1
    k_gcnmlp<<<NN / 256, 256, 0, stream>>>(aggH, xsH, dinv, W1, b1, W2);  // t2s over xsH

    (void)hipMemsetAsync(aggH, 0, (size_t)NN * 16 * sizeof(__half), stream);
    k_agg<<<8192, 256, 0, stream>>>(ei, xsH, aggH);                    // agg2

    dim3 gg(ROWD / 64, KCHUNKS);
    k_gemmA<<<gg, 256, 0, stream>>>(aggH, xsH, dinv, b2, Wih, gxp);
    k_lstm<<<BATCH, 128, 0, stream>>>(gxp, Whh, bih, bhh, hseq);
    k_fc<<<2, 256, 0, stream>>>(hseq, Wfc1, bfc1, Wfc2, bfc2, out);
}

// Round 17
// 325.825 us; speedup vs baseline: 1.8887x; 1.4156x over previous
//
#include <hip/hip_runtime.h>
#include <hip/hip_fp16.h>

#define NN      262144    // N = B*WIN_IN*NODES
#define EDGES   2097152
#define FEATD   16
#define HIDD    64
#define LSTMH   32
#define BATCH   64
#define WIN     32
#define WOUT    8
#define NCLS    10
#define ROWD    2048      // NODES*FEAT = B*WIN (both 2048)
#define KCHUNKS 8

#define NB      2048      // dest buckets: c >> 7
#define SH      8         // shards to cut counter contention
#define CAP     224       // per (bucket,shard); Poisson(128)+8.5 sigma
#define BCAP    (SH * CAP)   // 1792 per bucket (hard max, no overflow possible)

// ---- bucketize by DEST: bdata[(b*SH+s)*CAP+pos] = (r<<7)|(c&127), b=c>>7 ----
__global__ void k_bucketize(const int* __restrict__ ei, int* __restrict__ bcnt,
                            int* __restrict__ bdata) {
    int s = blockIdx.x & (SH - 1);
    int stride = gridDim.x * blockDim.x;
    for (int e = blockIdx.x * blockDim.x + threadIdx.x; e < EDGES; e += stride) {
        int r = ei[e];
        int c = ei[EDGES + e];
        int sb = (c >> 7) * SH + s;
        int pos = atomicAdd(&bcnt[sb], 1);
        if (pos < CAP) bdata[(size_t)sb * CAP + pos] = (r << 7) | (c & 127);
    }
}

// ---- per-bucket LDS counting sort -> dest-sorted rows, per-node end-offsets,
//      degrees (dinv) as byproduct. One block per bucket. ----
__global__ void __launch_bounds__(256)
k_csrsort(const int* __restrict__ bcnt, const int* __restrict__ bdata,
          int* __restrict__ rows, int* __restrict__ off, float* __restrict__ dinv) {
    __shared__ int sidx[BCAP];
    __shared__ int sorted[BCAP];
    __shared__ int hist[128], curp[128];
    __shared__ int seg[SH + 1];
    int b = blockIdx.x, tid = threadIdx.x;
    if (tid < 128) hist[tid] = 0;
    if (tid == 0) {
        int s = 0; seg[0] = 0;
#pragma unroll
        for (int k = 0; k < SH; k++) {
            int L = bcnt[b * SH + k]; if (L > CAP) L = CAP;
            s += L; seg[k + 1] = s;
        }
    }
    __syncthreads();
#pragma unroll
    for (int s = 0; s < SH; s++) {
        int o = seg[s], len = seg[s + 1] - o;
        const int* base = bdata + (size_t)(b * SH + s) * CAP;
        for (int i = tid; i < len; i += 256) sidx[o + i] = base[i];
    }
    __syncthreads();
    int total = seg[SH];
    for (int i = tid; i < total; i += 256) atomicAdd(&hist[sidx[i] & 127], 1);
    __syncthreads();
    if (tid == 0) {
        int run = 0;
#pragma unroll
        for (int co = 0; co < 128; co++) { curp[co] = run; run += hist[co]; }
    }
    __syncthreads();
    if (tid < 128) {
        off[b * 128 + tid] = curp[tid] + hist[tid];            // exclusive end
        dinv[b * 128 + tid] = rsqrtf((float)hist[tid] + 1.0f); // degree byproduct
    }
    __syncthreads();
    for (int i = tid; i < total; i += 256) {
        int w = sidx[i];
        int pos = atomicAdd(&curp[w & 127], 1);
        sorted[pos] = w >> 7;
    }
    __syncthreads();
    for (int i = tid; i < total; i += 256) rows[(size_t)b * BCAP + i] = sorted[i];
}

// ---- pre-scale: xsH[n][f2] = half2(x[n]*dinv[n]) ----
__global__ void k_scale(const float* __restrict__ x, const float* __restrict__ dinv,
                        __half2* __restrict__ xsH) {
    int i = blockIdx.x * blockDim.x + threadIdx.x;   // NN*8 half2 lanes
    if (i >= NN * 8) return;
    float d = dinv[i >> 3];
    float2 v = ((const float2*)x)[i];
    xsH[i] = __floats2half2_rn(v.x * d, v.y * d);
}

// ---- zero-atomic CSR gather-reduce, f32 accumulate, fused self (+b2,relu L2) ----
// thread = (node, f2): 2M lanes; per edge ONE random 32B gather, writes coalesced.
template<int LAYER>
__global__ void __launch_bounds__(256)
k_aggcsr(const int* __restrict__ rows, const int* __restrict__ off,
         const float* __restrict__ dinv, const __half2* __restrict__ srcH,
         const float* __restrict__ b2, __half2* __restrict__ outH) {
    int i = blockIdx.x * blockDim.x + threadIdx.x;
    if (i >= NN * 8) return;
    int n = i >> 3, f2 = i & 7;
    int begin = (n & 127) ? off[n - 1] : 0;
    int end = off[n];
    const int base = (n >> 7) * BCAP;
    float2 selfv = __half22float2(srcH[(size_t)n * 8 + f2]);
    float ax = selfv.x, ay = selfv.y;
    for (int e = base + begin; e < base + end; ++e) {
        int r = rows[e];
        float2 v = __half22float2(srcH[(size_t)r * 8 + f2]);
        ax += v.x; ay += v.y;
    }
    float d = dinv[n];
    ax *= d; ay *= d;
    if (LAYER == 2) {
        ax = fmaxf(ax + b2[f2 * 2 + 0], 0.f);
        ay = fmaxf(ay + b2[f2 * 2 + 1], 0.f);
    }
    outH[i] = __floats2half2_rn(ax, ay);
}

// ---- fused MLP: hid = relu(in1@W1+b1) ; t2s = (hid@W2)*dinv -> fp16 over xsH ----
__global__ void k_gcnmlp(const __half2* __restrict__ in1H, __half2* __restrict__ xsH,
                         const float* __restrict__ dinv,
                         const float* __restrict__ W1, const float* __restrict__ b1,
                         const float* __restrict__ W2) {
    __shared__ float sW1[FEATD * HIDD];
    __shared__ float sW2[HIDD * FEATD];
    __shared__ float sb1[HIDD];
    for (int l = threadIdx.x; l < FEATD * HIDD; l += blockDim.x) {
        sW1[l] = W1[l];
        sW2[l] = W2[l];
    }
    if (threadIdx.x < HIDD) sb1[threadIdx.x] = b1[threadIdx.x];
    __syncthreads();
    int n = blockIdx.x * blockDim.x + threadIdx.x;
    if (n >= NN) return;
    union { float4 f4; __half2 h2[4]; } a0, a1;
    a0.f4 = ((const float4*)(in1H + (size_t)n * 8))[0];
    a1.f4 = ((const float4*)(in1H + (size_t)n * 8))[1];
    float in[FEATD];
#pragma unroll
    for (int q = 0; q < 4; q++) {
        float2 v = __half22float2(a0.h2[q]);
        in[q * 2 + 0] = v.x; in[q * 2 + 1] = v.y;
        v = __half22float2(a1.h2[q]);
        in[8 + q * 2 + 0] = v.x; in[8 + q * 2 + 1] = v.y;
    }
    float out[FEATD];
#pragma unroll
    for (int c = 0; c < FEATD; c++) out[c] = 0.f;
#pragma unroll 8
    for (int j = 0; j < HIDD; j++) {
        float h = sb1[j];
#pragma unroll
        for (int f = 0; f < FEATD; f++) h += in[f] * sW1[f * HIDD + j];
        h = fmaxf(h, 0.f);
#pragma unroll
        for (int c = 0; c < FEATD; c++) out[c] += h * sW2[j * FEATD + c];
    }
    float dn = dinv[n];
    union { float4 f4; __half2 h2[4]; } o0, o1;
#pragma unroll
    for (int q = 0; q < 4; q++) {
        o0.h2[q] = __floats2half2_rn(out[q * 2] * dn, out[q * 2 + 1] * dn);
        o1.h2[q] = __floats2half2_rn(out[8 + q * 2] * dn, out[8 + q * 2 + 1] * dn);
    }
    ((float4*)(xsH + (size_t)n * 8))[0] = o0.f4;
    ((float4*)(xsH + (size_t)n * 8))[1] = o1.f4;
}

// ---- LSTM input GEMM: A = h2 (fp16, final), B = Wih ----
#define KT 32
__global__ void k_gemmA(const __half2* __restrict__ h2H, const float* __restrict__ Wih,
                        float* __restrict__ gxp) {
    __shared__ float As[64][KT + 1];
    __shared__ float Bs[128][KT + 1];
    int tid = threadIdx.x;
    int tx = tid & 15, ty = tid >> 4;
    float acc[4][8];
#pragma unroll
    for (int i = 0; i < 4; i++)
#pragma unroll
        for (int j = 0; j < 8; j++) acc[i][j] = 0.f;
    int row0 = blockIdx.x * 64;
    int k0 = blockIdx.y * (ROWD / KCHUNKS);
    const __half* h2 = (const __half*)h2H;
    for (int kk = 0; kk < ROWD / KCHUNKS; kk += KT) {
        {   // A tile: 64 x 32 halfs; 256 threads x 8 halfs
            int rr = tid >> 2;
            int cc = (tid & 3) * 8;
            size_t flat = (size_t)(row0 + rr) * ROWD + k0 + kk + cc;
            union { float4 f4; __half2 h2v[4]; } a;
            a.f4 = *(const float4*)(h2 + flat);
#pragma unroll
            for (int q = 0; q < 4; q++) {
                float2 v = __half22float2(a.h2v[q]);
                As[rr][cc + q * 2 + 0] = v.x;
                As[rr][cc + q * 2 + 1] = v.y;
            }
        }
        for (int l = tid; l < 128 * KT / 4; l += 256) {
            int rr = l >> 3;
            int cc = (l & 7) * 4;
            float4 v = *(const float4*)&Wih[(size_t)rr * ROWD + k0 + kk + cc];
            Bs[rr][cc + 0] = v.x; Bs[rr][cc + 1] = v.y; Bs[rr][cc + 2] = v.z; Bs[rr][cc + 3] = v.w;
        }
        __syncthreads();
#pragma unroll
        for (int k = 0; k < KT; k++) {
            float a[4], bb[8];
#pragma unroll
            for (int i = 0; i < 4; i++) a[i] = As[ty * 4 + i][k];
#pragma unroll
            for (int j = 0; j < 8; j++) bb[j] = Bs[tx * 8 + j][k];
#pragma unroll
            for (int i = 0; i < 4; i++)
#pragma unroll
                for (int j = 0; j < 8; j++) acc[i][j] += a[i] * bb[j];
        }
        __syncthreads();
    }
    float* outp = gxp + (size_t)blockIdx.y * (ROWD * 128);
#pragma unroll
    for (int i = 0; i < 4; i++)
#pragma unroll
        for (int j = 0; j < 8; j++)
            outp[(size_t)(row0 + ty * 4 + i) * 128 + tx * 8 + j] = acc[i][j];
}

// ---- gxp partial-sum prereduce: sgx[row*128+j] = sum_p gxp[p][row][j] ----
__global__ void k_pre(const float* __restrict__ gxp, float* __restrict__ sgx) {
    int i = blockIdx.x * blockDim.x + threadIdx.x;   // ROWD*128 lanes
    if (i >= ROWD * 128) return;
    float s = 0.f;
#pragma unroll
    for (int p = 0; p < KCHUNKS; p++) s += gxp[(size_t)p * ROWD * 128 + i];
    sgx[i] = s;
}

// ---- LSTM recurrence (reads pre-summed sgx) ----
__global__ void k_lstm(const float* __restrict__ sgx, const float* __restrict__ Whh,
                       const float* __restrict__ bih, const float* __restrict__ bhh,
                       float* __restrict__ hseq) {
    __shared__ float sWhhT[LSTMH][4 * LSTMH];   // [k][j] = Whh[j][k]
    __shared__ float sgxL[WIN * 4 * LSTMH];      // 16 KB
    __shared__ float sh[LSTMH], sc[LSTMH], sg[4 * LSTMH];
    int b = blockIdx.x, j = threadIdx.x;
    for (int l = j; l < 4 * LSTMH * LSTMH; l += 4 * LSTMH) {
        int r = l >> 5, k = l & 31;
        sWhhT[k][r] = Whh[l];
    }
    for (int l = j; l < WIN * 128; l += 128) sgxL[l] = sgx[(size_t)b * WIN * 128 + l];
    float bias = bih[j] + bhh[j];
    if (j < LSTMH) { sh[j] = 0.f; sc[j] = 0.f; }
    __syncthreads();
    for (int t = 0; t < WIN; t++) {
        float g = bias + sgxL[t * 128 + j];
#pragma unroll
        for (int k = 0; k < LSTMH; k++) g += sWhhT[k][j] * sh[k];
        sg[j] = g;
        __syncthreads();
        if (j < LSTMH) {
            float ig = sg[j], fg = sg[32 + j], gg = sg[64 + j], og = sg[96 + j];
            float c = sc[j];
            float si = 1.f / (1.f + __expf(-ig));
            float sf = 1.f / (1.f + __expf(-fg));
            float so = 1.f / (1.f + __expf(-og));
            c = sf * c + si * tanhf(gg);
            float h = so * tanhf(c);
            sc[j] = c; sh[j] = h;
            if (t >= WIN - WOUT)
                hseq[(size_t)(b * WOUT + (t - (WIN - WOUT))) * LSTMH + j] = h;
        }
        __syncthreads();
    }
}

// ---- FC head: (512 rows) 32 -> 16 relu -> 10 ----
__global__ void k_fc(const float* __restrict__ hseq, const float* __restrict__ Wfc1,
                     const float* __restrict__ bfc1, const float* __restrict__ Wfc2,
                     const float* __restrict__ bfc2, float* __restrict__ out) {
    __shared__ float sW1[16 * 32], sb1[16], sW2[10 * 16], sb2[10];
    int tid = threadIdx.x;
    for (int l = tid; l < 16 * 32; l += blockDim.x) sW1[l] = Wfc1[l];
    if (tid < 16) sb1[tid] = bfc1[tid];
    for (int l = tid; l < 160; l += blockDim.x) sW2[l] = Wfc2[l];
    if (tid < 10) sb2[tid] = bfc2[tid];
    __syncthreads();
    int r = blockIdx.x * blockDim.x + tid;
    if (r >= BATCH * WOUT) return;
    float h[32];
#pragma unroll
    for (int k = 0; k < 32; k++) h[k] = hseq[(size_t)r * 32 + k];
    float hid[16];
#pragma unroll
    for (int j = 0; j < 16; j++) {
        float v = sb1[j];
#pragma unroll
        for (int k = 0; k < 32; k++) v += sW1[j * 32 + k] * h[k];
        hid[j] = fmaxf(v, 0.f);
    }
#pragma unroll
    for (int c = 0; c < NCLS; c++) {
        float v = sb2[c];
#pragma unroll
        for (int j = 0; j < 16; j++) v += sW2[c * 16 + j] * hid[j];
        out[(size_t)r * NCLS + c] = v;
    }
}

extern "C" void kernel_launch(void* const* d_in, const int* in_sizes, int n_in,
                              void* d_out, int out_size, void* d_ws, size_t ws_size,
                              hipStream_t stream) {
    const float* x    = (const float*)d_in[0];
    const int*   ei   = (const int*)d_in[1];
    const float* W1   = (const float*)d_in[2];
    const float* b1   = (const float*)d_in[3];
    const float* W2   = (const float*)d_in[4];
    const float* b2   = (const float*)d_in[5];
    const float* Wih  = (const float*)d_in[6];
    const float* Whh  = (const float*)d_in[7];
    const float* bih  = (const float*)d_in[8];
    const float* bhh  = (const float*)d_in[9];
    const float* Wfc1 = (const float*)d_in[10];
    const float* bfc1 = (const float*)d_in[11];
    const float* Wfc2 = (const float*)d_in[12];
    const float* bfc2 = (const float*)d_in[13];
    float* out = (float*)d_out;

    float*   ws    = (float*)d_ws;
    float*   dinv  = ws;                                    // NN f32 (1 MB)
    int*     bcnt  = (int*)(dinv + NN);                     // NB*SH ints (64 KB)
    int*     off   = bcnt + NB * SH;                        // NN ints (1 MB)
    int*     rows  = off + NN;                              // NB*BCAP ints (14.7 MB)
    __half2* aggH  = (__half2*)(rows + (size_t)NB * BCAP);  // NN*8 half2 (8 MB): in1/h2
    __half2* xsH   = aggH + (size_t)NN * 8;                 // NN*8 half2 (8 MB): xs -> t2s
    int*     bdata = (int*)(xsH + (size_t)NN * 8);          // NB*SH*CAP ints (14.7 MB)
    float*   gxp   = (float*)bdata;                         // 8 MB, aliases bdata (dead)
    float*   sgx   = gxp + (size_t)KCHUNKS * ROWD * 128;    // 1 MB
    float*   hseq  = sgx + ROWD * 128;                      // 64 KB

    (void)hipMemsetAsync(bcnt, 0, NB * SH * sizeof(int), stream);
    k_bucketize<<<2048, 256, 0, stream>>>(ei, bcnt, bdata);
    k_csrsort<<<NB, 256, 0, stream>>>(bcnt, bdata, rows, off, dinv);
    k_scale<<<NN * 8 / 256, 256, 0, stream>>>(x, dinv, xsH);

    k_aggcsr<1><<<NN * 8 / 256, 256, 0, stream>>>(rows, off, dinv, xsH, b2, aggH);  // in1
    k_gcnmlp<<<NN / 256, 256, 0, stream>>>(aggH, xsH, dinv, W1, b1, W2);            // t2s
    k_aggcsr<2><<<NN * 8 / 256, 256, 0, stream>>>(rows, off, dinv, xsH, b2, aggH);  // h2

    dim3 gg(ROWD / 64, KCHUNKS);
    k_gemmA<<<gg, 256, 0, stream>>>(aggH, Wih, gxp);
    k_pre<<<ROWD * 128 / 256, 256, 0, stream>>>(gxp, sgx);
    k_lstm<<<BATCH, 128, 0, stream>>>(sgx, Whh, bih, bhh, hseq);
    k_fc<<<2, 256, 0, stream>>>(hseq, Wfc1, bfc1, Wfc2, bfc2, out);
}

// Round 18
// 285.503 us; speedup vs baseline: 2.1554x; 1.1412x over previous
//
#include <hip/hip_runtime.h>
#include <hip/hip_fp16.h>

#define NN      262144    // N = B*WIN_IN*NODES
#define EDGES   2097152
#define FEATD   16
#define HIDD    64
#define LSTMH   32
#define BATCH   64
#define WIN     32
#define WOUT    8
#define NCLS    10
#define ROWD    2048      // NODES*FEAT = B*WIN (both 2048)
#define KCHUNKS 8

#define NB2     512       // dest buckets: c >> 9 (512 nodes each)
#define NW      512       // nodes per bucket
#define CAPB    4608      // per-bucket capacity: Poisson(4096)+8 sigma
#define NBLK    256       // edge chunks
#define CHUNK   (EDGES / NBLK)   // 8192 edges per chunk

// ---- phase 1: per-(block,bucket) histogram ----
__global__ void k_hist(const int* __restrict__ ei, int* __restrict__ hist2d) {
    __shared__ int h[NB2];
    int blk = blockIdx.x, tid = threadIdx.x;
    for (int l = tid; l < NB2; l += 256) h[l] = 0;
    __syncthreads();
    int e0 = blk * CHUNK;
    for (int i = tid; i < CHUNK; i += 256)
        atomicAdd(&h[ei[EDGES + e0 + i] >> 9], 1);
    __syncthreads();
    for (int l = tid; l < NB2; l += 256) hist2d[l * NBLK + blk] = h[l];
}

// ---- phase 2: per-bucket exclusive scan over block counts; totals -> bcnt ----
__global__ void k_scan2(int* __restrict__ hist2d, int* __restrict__ bcnt) {
    __shared__ int s[NBLK];
    int b = blockIdx.x, tid = threadIdx.x;
    int v = hist2d[b * NBLK + tid];
    s[tid] = v;
    __syncthreads();
    for (int off = 1; off < NBLK; off <<= 1) {
        int t = (tid >= off) ? s[tid - off] : 0;
        __syncthreads();
        s[tid] += t;
        __syncthreads();
    }
    hist2d[b * NBLK + tid] = s[tid] - v;   // exclusive base for (bucket, block)
    if (tid == NBLK - 1) bcnt[b] = s[tid];
}

// ---- phase 3: place edges into block-private contiguous runs (full lines) ----
__global__ void k_place(const int* __restrict__ ei, const int* __restrict__ hist2d,
                        int* __restrict__ bdata) {
    __shared__ int curp[NB2];
    int blk = blockIdx.x, tid = threadIdx.x;
    for (int l = tid; l < NB2; l += 256) curp[l] = hist2d[l * NBLK + blk];
    __syncthreads();
    int e0 = blk * CHUNK;
    for (int i = tid; i < CHUNK; i += 256) {
        int r = ei[e0 + i];
        int c = ei[EDGES + e0 + i];
        int b = c >> 9;
        int p = atomicAdd(&curp[b], 1);
        if (p < CAPB) bdata[(size_t)b * CAPB + p] = (r << 9) | (c & 511);
    }
}

// ---- per-bucket LDS counting sort -> dest-sorted rows, offsets, degrees ----
__global__ void __launch_bounds__(256)
k_csrsort(const int* __restrict__ bcnt, const int* __restrict__ bdata,
          int* __restrict__ rows, int* __restrict__ off, float* __restrict__ dinv) {
    __shared__ int sidx[CAPB];          // 18.4 KB
    __shared__ int hist[NW], curp[NW];  // 4 KB
    int b = blockIdx.x, tid = threadIdx.x;
    int total = bcnt[b]; if (total > CAPB) total = CAPB;
    for (int l = tid; l < NW; l += 256) hist[l] = 0;
    __syncthreads();
    const int* base = bdata + (size_t)b * CAPB;
    for (int i = tid; i < total; i += 256) {
        int w = base[i];
        sidx[i] = w;
        atomicAdd(&hist[w & 511], 1);
    }
    __syncthreads();
    if (tid == 0) {
        int run = 0;
        for (int co = 0; co < NW; co++) { curp[co] = run; run += hist[co]; }
    }
    __syncthreads();
    for (int l = tid; l < NW; l += 256) {
        off[b * NW + l] = curp[l] + hist[l];                 // exclusive end
        dinv[b * NW + l] = rsqrtf((float)hist[l] + 1.0f);    // degree byproduct
    }
    __syncthreads();
    for (int i = tid; i < total; i += 256) {
        int w = sidx[i];
        int pos = atomicAdd(&curp[w & 511], 1);
        rows[(size_t)b * CAPB + pos] = w >> 9;               // block-local 18KB window
    }
}

// ---- pre-scale: xsH[n][f2] = half2(x[n]*dinv[n]) ----
__global__ void k_scale(const float* __restrict__ x, const float* __restrict__ dinv,
                        __half2* __restrict__ xsH) {
    int i = blockIdx.x * blockDim.x + threadIdx.x;   // NN*8 half2 lanes
    if (i >= NN * 8) return;
    float d = dinv[i >> 3];
    float2 v = ((const float2*)x)[i];
    xsH[i] = __floats2half2_rn(v.x * d, v.y * d);
}

// ---- zero-atomic CSR gather-reduce, f32 accumulate, fused self (+b2,relu L2) ----
template<int LAYER>
__global__ void __launch_bounds__(256)
k_aggcsr(const int* __restrict__ rows, const int* __restrict__ off,
         const float* __restrict__ dinv, const __half2* __restrict__ srcH,
         const float* __restrict__ b2, __half2* __restrict__ outH) {
    int i = blockIdx.x * blockDim.x + threadIdx.x;
    if (i >= NN * 8) return;
    int n = i >> 3, f2 = i & 7;
    int begin = (n & 511) ? off[n - 1] : 0;
    int end = off[n];
    const size_t base = (size_t)(n >> 9) * CAPB;
    float2 selfv = __half22float2(srcH[(size_t)n * 8 + f2]);
    float ax = selfv.x, ay = selfv.y;
    for (size_t e = base + begin; e < base + end; ++e) {
        int r = rows[e];
        float2 v = __half22float2(srcH[(size_t)r * 8 + f2]);
        ax += v.x; ay += v.y;
    }
    float d = dinv[n];
    ax *= d; ay *= d;
    if (LAYER == 2) {
        ax = fmaxf(ax + b2[f2 * 2 + 0], 0.f);
        ay = fmaxf(ay + b2[f2 * 2 + 1], 0.f);
    }
    outH[i] = __floats2half2_rn(ax, ay);
}

// ---- fused MLP: hid = relu(in1@W1+b1) ; t2s = (hid@W2)*dinv -> fp16 over xsH ----
__global__ void k_gcnmlp(const __half2* __restrict__ in1H, __half2* __restrict__ xsH,
                         const float* __restrict__ dinv,
                         const float* __restrict__ W1, const float* __restrict__ b1,
                         const float* __restrict__ W2) {
    __shared__ float sW1[FEATD * HIDD];
    __shared__ float sW2[HIDD * FEATD];
    __shared__ float sb1[HIDD];
    for (int l = threadIdx.x; l < FEATD * HIDD; l += blockDim.x) {
        sW1[l] = W1[l];
        sW2[l] = W2[l];
    }
    if (threadIdx.x < HIDD) sb1[threadIdx.x] = b1[threadIdx.x];
    __syncthreads();
    int n = blockIdx.x * blockDim.x + threadIdx.x;
    if (n >= NN) return;
    union { float4 f4; __half2 h2[4]; } a0, a1;
    a0.f4 = ((const float4*)(in1H + (size_t)n * 8))[0];
    a1.f4 = ((const float4*)(in1H + (size_t)n * 8))[1];
    float in[FEATD];
#pragma unroll
    for (int q = 0; q < 4; q++) {
        float2 v = __half22float2(a0.h2[q]);
        in[q * 2 + 0] = v.x; in[q * 2 + 1] = v.y;
        v = __half22float2(a1.h2[q]);
        in[8 + q * 2 + 0] = v.x; in[8 + q * 2 + 1] = v.y;
    }
    float out[FEATD];
#pragma unroll
    for (int c = 0; c < FEATD; c++) out[c] = 0.f;
#pragma unroll 8
    for (int j = 0; j < HIDD; j++) {
        float h = sb1[j];
#pragma unroll
        for (int f = 0; f < FEATD; f++) h += in[f] * sW1[f * HIDD + j];
        h = fmaxf(h, 0.f);
#pragma unroll
        for (int c = 0; c < FEATD; c++) out[c] += h * sW2[j * FEATD + c];
    }
    float dn = dinv[n];
    union { float4 f4; __half2 h2[4]; } o0, o1;
#pragma unroll
    for (int q = 0; q < 4; q++) {
        o0.h2[q] = __floats2half2_rn(out[q * 2] * dn, out[q * 2 + 1] * dn);
        o1.h2[q] = __floats2half2_rn(out[8 + q * 2] * dn, out[8 + q * 2 + 1] * dn);
    }
    ((float4*)(xsH + (size_t)n * 8))[0] = o0.f4;
    ((float4*)(xsH + (size_t)n * 8))[1] = o1.f4;
}

// ---- LSTM input GEMM: A = h2 (fp16, final), B = Wih ----
#define KT 32
__global__ void k_gemmA(const __half2* __restrict__ h2H, const float* __restrict__ Wih,
                        float* __restrict__ gxp) {
    __shared__ float As[64][KT + 1];
    __shared__ float Bs[128][KT + 1];
    int tid = threadIdx.x;
    int tx = tid & 15, ty = tid >> 4;
    float acc[4][8];
#pragma unroll
    for (int i = 0; i < 4; i++)
#pragma unroll
        for (int j = 0; j < 8; j++) acc[i][j] = 0.f;
    int row0 = blockIdx.x * 64;
    int k0 = blockIdx.y * (ROWD / KCHUNKS);
    const __half* h2 = (const __half*)h2H;
    for (int kk = 0; kk < ROWD / KCHUNKS; kk += KT) {
        {   // A tile: 64 x 32 halfs; 256 threads x 8 halfs
            int rr = tid >> 2;
            int cc = (tid & 3) * 8;
            size_t flat = (size_t)(row0 + rr) * ROWD + k0 + kk + cc;
            union { float4 f4; __half2 h2v[4]; } a;
            a.f4 = *(const float4*)(h2 + flat);
#pragma unroll
            for (int q = 0; q < 4; q++) {
                float2 v = __half22float2(a.h2v[q]);
                As[rr][cc + q * 2 + 0] = v.x;
                As[rr][cc + q * 2 + 1] = v.y;
            }
        }
        for (int l = tid; l < 128 * KT / 4; l += 256) {
            int rr = l >> 3;
            int cc = (l & 7) * 4;
            float4 v = *(const float4*)&Wih[(size_t)rr * ROWD + k0 + kk + cc];
            Bs[rr][cc + 0] = v.x; Bs[rr][cc + 1] = v.y; Bs[rr][cc + 2] = v.z; Bs[rr][cc + 3] = v.w;
        }
        __syncthreads();
#pragma unroll
        for (int k = 0; k < KT; k++) {
            float a[4], bb[8];
#pragma unroll
            for (int i = 0; i < 4; i++) a[i] = As[ty * 4 + i][k];
#pragma unroll
            for (int j = 0; j < 8; j++) bb[j] = Bs[tx * 8 + j][k];
#pragma unroll
            for (int i = 0; i < 4; i++)
#pragma unroll
                for (int j = 0; j < 8; j++) acc[i][j] += a[i] * bb[j];
        }
        __syncthreads();
    }
    float* outp = gxp + (size_t)blockIdx.y * (ROWD * 128);
#pragma unroll
    for (int i = 0; i < 4; i++)
#pragma unroll
        for (int j = 0; j < 8; j++)
            outp[(size_t)(row0 + ty * 4 + i) * 128 + tx * 8 + j] = acc[i][j];
}

// ---- gxp partial-sum prereduce ----
__global__ void k_pre(const float* __restrict__ gxp, float* __restrict__ sgx) {
    int i = blockIdx.x * blockDim.x + threadIdx.x;   // ROWD*128 lanes
    if (i >= ROWD * 128) return;
    float s = 0.f;
#pragma unroll
    for (int p = 0; p < KCHUNKS; p++) s += gxp[(size_t)p * ROWD * 128 + i];
    sgx[i] = s;
}

// ---- LSTM recurrence (reads pre-summed sgx) ----
__global__ void k_lstm(const float* __restrict__ sgx, const float* __restrict__ Whh,
                       const float* __restrict__ bih, const float* __restrict__ bhh,
                       float* __restrict__ hseq) {
    __shared__ float sWhhT[LSTMH][4 * LSTMH];   // [k][j] = Whh[j][k]
    __shared__ float sgxL[WIN * 4 * LSTMH];      // 16 KB
    __shared__ float sh[LSTMH], sc[LSTMH], sg[4 * LSTMH];
    int b = blockIdx.x, j = threadIdx.x;
    for (int l = j; l < 4 * LSTMH * LSTMH; l += 4 * LSTMH) {
        int r = l >> 5, k = l & 31;
        sWhhT[k][r] = Whh[l];
    }
    for (int l = j; l < WIN * 128; l += 128) sgxL[l] = sgx[(size_t)b * WIN * 128 + l];
    float bias = bih[j] + bhh[j];
    if (j < LSTMH) { sh[j] = 0.f; sc[j] = 0.f; }
    __syncthreads();
    for (int t = 0; t < WIN; t++) {
        float g = bias + sgxL[t * 128 + j];
#pragma unroll
        for (int k = 0; k < LSTMH; k++) g += sWhhT[k][j] * sh[k];
        sg[j] = g;
        __syncthreads();
        if (j < LSTMH) {
            float ig = sg[j], fg = sg[32 + j], gg = sg[64 + j], og = sg[96 + j];
            float c = sc[j];
            float si = 1.f / (1.f + __expf(-ig));
            float sf = 1.f / (1.f + __expf(-fg));
            float so = 1.f / (1.f + __expf(-og));
            c = sf * c + si * tanhf(gg);
            float h = so * tanhf(c);
            sc[j] = c; sh[j] = h;
            if (t >= WIN - WOUT)
                hseq[(size_t)(b * WOUT + (t - (WIN - WOUT))) * LSTMH + j] = h;
        }
        __syncthreads();
    }
}

// ---- FC head: (512 rows) 32 -> 16 relu -> 10 ----
__global__ void k_fc(const float* __restrict__ hseq, const float* __restrict__ Wfc1,
                     const float* __restrict__ bfc1, const float* __restrict__ Wfc2,
                     const float* __restrict__ bfc2, float* __restrict__ out) {
    __shared__ float sW1[16 * 32], sb1[16], sW2[10 * 16], sb2[10];
    int tid = threadIdx.x;
    for (int l = tid; l < 16 * 32; l += blockDim.x) sW1[l] = Wfc1[l];
    if (tid < 16) sb1[tid] = bfc1[tid];
    for (int l = tid; l < 160; l += blockDim.x) sW2[l] = Wfc2[l];
    if (tid < 10) sb2[tid] = bfc2[tid];
    __syncthreads();
    int r = blockIdx.x * blockDim.x + tid;
    if (r >= BATCH * WOUT) return;
    float h[32];
#pragma unroll
    for (int k = 0; k < 32; k++) h[k] = hseq[(size_t)r * 32 + k];
    float hid[16];
#pragma unroll
    for (int j = 0; j < 16; j++) {
        float v = sb1[j];
#pragma unroll
        for (int k = 0; k < 32; k++) v += sW1[j * 32 + k] * h[k];
        hid[j] = fmaxf(v, 0.f);
    }
#pragma unroll
    for (int c = 0; c < NCLS; c++) {
        float v = sb2[c];
#pragma unroll
        for (int j = 0; j < 16; j++) v += sW2[c * 16 + j] * hid[j];
        out[(size_t)r * NCLS + c] = v;
    }
}

extern "C" void kernel_launch(void* const* d_in, const int* in_sizes, int n_in,
                              void* d_out, int out_size, void* d_ws, size_t ws_size,
                              hipStream_t stream) {
    const float* x    = (const float*)d_in[0];
    const int*   ei   = (const int*)d_in[1];
    const float* W1   = (const float*)d_in[2];
    const float* b1   = (const float*)d_in[3];
    const float* W2   = (const float*)d_in[4];
    const float* b2   = (const float*)d_in[5];
    const float* Wih  = (const float*)d_in[6];
    const float* Whh  = (const float*)d_in[7];
    const float* bih  = (const float*)d_in[8];
    const float* bhh  = (const float*)d_in[9];
    const float* Wfc1 = (const float*)d_in[10];
    const float* bfc1 = (const float*)d_in[11];
    const float* Wfc2 = (const float*)d_in[12];
    const float* bfc2 = (const float*)d_in[13];
    float* out = (float*)d_out;

    float*   ws     = (float*)d_ws;
    float*   dinv   = ws;                                    // NN f32 (1 MB)
    int*     hist2d = (int*)(dinv + NN);                     // NB2*NBLK ints (0.5 MB)
    int*     bcnt   = hist2d + NB2 * NBLK;                   // NB2 ints
    int*     off    = bcnt + NB2;                            // NN ints (1 MB)
    int*     rows   = off + NN;                              // NB2*CAPB ints (9.4 MB)
    __half2* aggH   = (__half2*)(rows + (size_t)NB2 * CAPB); // NN*8 half2 (8 MB)
    __half2* xsH    = aggH + (size_t)NN * 8;                 // NN*8 half2 (8 MB)
    int*     bdata  = (int*)(xsH + (size_t)NN * 8);          // NB2*CAPB ints (9.4 MB)
    float*   gxp    = (float*)bdata;                         // 8 MB, aliases bdata (dead after csrsort)
    float*   sgx    = (float*)(bdata + (size_t)NB2 * CAPB);  // 1 MB
    float*   hseq   = sgx + ROWD * 128;                      // 64 KB

    k_hist<<<NBLK, 256, 0, stream>>>(ei, hist2d);
    k_scan2<<<NB2, NBLK, 0, stream>>>(hist2d, bcnt);
    k_place<<<NBLK, 256, 0, stream>>>(ei, hist2d, bdata);
    k_csrsort<<<NB2, 256, 0, stream>>>(bcnt, bdata, rows, off, dinv);
    k_scale<<<NN * 8 / 256, 256, 0, stream>>>(x, dinv, xsH);

    k_aggcsr<1><<<NN * 8 / 256, 256, 0, stream>>>(rows, off, dinv, xsH, b2, aggH);  // in1
    k_gcnmlp<<<NN / 256, 256, 0, stream>>>(aggH, xsH, dinv, W1, b1, W2);            // t2s
    k_aggcsr<2><<<NN * 8 / 256, 256, 0, stream>>>(rows, off, dinv, xsH, b2, aggH);  // h2

    dim3 gg(ROWD / 64, KCHUNKS);
    k_gemmA<<<gg, 256, 0, stream>>>(aggH, Wih, gxp);
    k_pre<<<ROWD * 128 / 256, 256, 0, stream>>>(gxp, sgx);
    k_lstm<<<BATCH, 128, 0, stream>>>(sgx, Whh, bih, bhh, hseq);
    k_fc<<<2, 256, 0, stream>>>(hseq, Wfc1, bfc1, Wfc2, bfc2, out);
}

// Round 19
// 263.491 us; speedup vs baseline: 2.3355x; 1.0835x over previous
//
#include <hip/hip_runtime.h>
#include <hip/hip_fp16.h>

#define NN      262144    // N = B*WIN_IN*NODES
#define EDGES   2097152
#define FEATD   16
#define HIDD    64
#define LSTMH   32
#define BATCH   64
#define WIN     32
#define WOUT    8
#define NCLS    10
#define ROWD    2048      // NODES*FEAT = B*WIN (both 2048)
#define KCHUNKS 8

#define NB2     512       // dest buckets: c >> 9 (512 nodes each)
#define NW      512       // nodes per bucket
#define CAPB    4608      // per-bucket capacity: Poisson(4096)+8 sigma
#define NBLK    256       // edge chunks
#define CHUNK   (EDGES / NBLK)   // 8192 edges per chunk

// ---- phase 1: per-(block,bucket) histogram ----
__global__ void k_hist(const int* __restrict__ ei, int* __restrict__ hist2d) {
    __shared__ int h[NB2];
    int blk = blockIdx.x, tid = threadIdx.x;
    for (int l = tid; l < NB2; l += 256) h[l] = 0;
    __syncthreads();
    int e0 = blk * CHUNK;
    for (int i = tid; i < CHUNK; i += 256)
        atomicAdd(&h[ei[EDGES + e0 + i] >> 9], 1);
    __syncthreads();
    for (int l = tid; l < NB2; l += 256) hist2d[l * NBLK + blk] = h[l];
}

// ---- phase 2: per-bucket exclusive scan over block counts; totals -> bcnt ----
__global__ void k_scan2(int* __restrict__ hist2d, int* __restrict__ bcnt) {
    __shared__ int s[NBLK];
    int b = blockIdx.x, tid = threadIdx.x;
    int v = hist2d[b * NBLK + tid];
    s[tid] = v;
    __syncthreads();
    for (int off = 1; off < NBLK; off <<= 1) {
        int t = (tid >= off) ? s[tid - off] : 0;
        __syncthreads();
        s[tid] += t;
        __syncthreads();
    }
    hist2d[b * NBLK + tid] = s[tid] - v;   // exclusive base for (bucket, block)
    if (tid == NBLK - 1) bcnt[b] = s[tid];
}

// ---- phase 3: place edges into block-private contiguous runs (full lines) ----
__global__ void k_place(const int* __restrict__ ei, const int* __restrict__ hist2d,
                        int* __restrict__ bdata) {
    __shared__ int curp[NB2];
    int blk = blockIdx.x, tid = threadIdx.x;
    for (int l = tid; l < NB2; l += 256) curp[l] = hist2d[l * NBLK + blk];
    __syncthreads();
    int e0 = blk * CHUNK;
    for (int i = tid; i < CHUNK; i += 256) {
        int r = ei[e0 + i];
        int c = ei[EDGES + e0 + i];
        int b = c >> 9;
        int p = atomicAdd(&curp[b], 1);
        if (p < CAPB) bdata[(size_t)b * CAPB + p] = (r << 9) | (c & 511);
    }
}

// ---- per-bucket LDS counting sort -> dest-sorted rows, offsets, degrees ----
__global__ void __launch_bounds__(256)
k_csrsort(const int* __restrict__ bcnt, const int* __restrict__ bdata,
          int* __restrict__ rows, int* __restrict__ off, float* __restrict__ dinv) {
    __shared__ int sidx[CAPB];          // 18.4 KB
    __shared__ int hist[NW], curp[NW];  // 4 KB
    int b = blockIdx.x, tid = threadIdx.x;
    int total = bcnt[b]; if (total > CAPB) total = CAPB;
    for (int l = tid; l < NW; l += 256) hist[l] = 0;
    __syncthreads();
    const int* base = bdata + (size_t)b * CAPB;
    for (int i = tid; i < total; i += 256) {
        int w = base[i];
        sidx[i] = w;
        atomicAdd(&hist[w & 511], 1);
    }
    __syncthreads();
    if (tid == 0) {
        int run = 0;
        for (int co = 0; co < NW; co++) { curp[co] = run; run += hist[co]; }
    }
    __syncthreads();
    for (int l = tid; l < NW; l += 256) {
        off[b * NW + l] = curp[l] + hist[l];                 // exclusive end
        dinv[b * NW + l] = rsqrtf((float)hist[l] + 1.0f);    // degree byproduct
    }
    __syncthreads();
    for (int i = tid; i < total; i += 256) {
        int w = sidx[i];
        int pos = atomicAdd(&curp[w & 511], 1);
        rows[(size_t)b * CAPB + pos] = w >> 9;               // block-local 18KB window
    }
}

// ---- pre-scale: xsH[n][f2] = half2(x[n]*dinv[n]) ----
__global__ void k_scale(const float* __restrict__ x, const float* __restrict__ dinv,
                        __half2* __restrict__ xsH) {
    int i = blockIdx.x * blockDim.x + threadIdx.x;   // NN*8 half2 lanes
    if (i >= NN * 8) return;
    float d = dinv[i >> 3];
    float2 v = ((const float2*)x)[i];
    xsH[i] = __floats2half2_rn(v.x * d, v.y * d);
}

// ---- zero-atomic CSR gather-reduce, f32 accumulate, fused self (+b2,relu L2) ----
template<int LAYER>
__global__ void __launch_bounds__(256)
k_aggcsr(const int* __restrict__ rows, const int* __restrict__ off,
         const float* __restrict__ dinv, const __half2* __restrict__ srcH,
         const float* __restrict__ b2, __half2* __restrict__ outH) {
    int i = blockIdx.x * blockDim.x + threadIdx.x;
    if (i >= NN * 8) return;
    int n = i >> 3, f2 = i & 7;
    int begin = (n & 511) ? off[n - 1] : 0;
    int end = off[n];
    const size_t base = (size_t)(n >> 9) * CAPB;
    float2 selfv = __half22float2(srcH[(size_t)n * 8 + f2]);
    float ax = selfv.x, ay = selfv.y;
    for (size_t e = base + begin; e < base + end; ++e) {
        int r = rows[e];
        float2 v = __half22float2(srcH[(size_t)r * 8 + f2]);
        ax += v.x; ay += v.y;
    }
    float d = dinv[n];
    ax *= d; ay *= d;
    if (LAYER == 2) {
        ax = fmaxf(ax + b2[f2 * 2 + 0], 0.f);
        ay = fmaxf(ay + b2[f2 * 2 + 1], 0.f);
    }
    outH[i] = __floats2half2_rn(ax, ay);
}

// ---- fused MLP: hid = relu(in1@W1+b1) ; t2s = (hid@W2)*dinv -> fp16 over xsH ----
__global__ void k_gcnmlp(const __half2* __restrict__ in1H, __half2* __restrict__ xsH,
                         const float* __restrict__ dinv,
                         const float* __restrict__ W1, const float* __restrict__ b1,
                         const float* __restrict__ W2) {
    __shared__ float sW1[FEATD * HIDD];
    __shared__ float sW2[HIDD * FEATD];
    __shared__ float sb1[HIDD];
    for (int l = threadIdx.x; l < FEATD * HIDD; l += blockDim.x) {
        sW1[l] = W1[l];
        sW2[l] = W2[l];
    }
    if (threadIdx.x < HIDD) sb1[threadIdx.x] = b1[threadIdx.x];
    __syncthreads();
    int n = blockIdx.x * blockDim.x + threadIdx.x;
    if (n >= NN) return;
    union { float4 f4; __half2 h2[4]; } a0, a1;
    a0.f4 = ((const float4*)(in1H + (size_t)n * 8))[0];
    a1.f4 = ((const float4*)(in1H + (size_t)n * 8))[1];
    float in[FEATD];
#pragma unroll
    for (int q = 0; q < 4; q++) {
        float2 v = __half22float2(a0.h2[q]);
        in[q * 2 + 0] = v.x; in[q * 2 + 1] = v.y;
        v = __half22float2(a1.h2[q]);
        in[8 + q * 2 + 0] = v.x; in[8 + q * 2 + 1] = v.y;
    }
    float out[FEATD];
#pragma unroll
    for (int c = 0; c < FEATD; c++) out[c] = 0.f;
#pragma unroll 8
    for (int j = 0; j < HIDD; j++) {
        float h = sb1[j];
#pragma unroll
        for (int f = 0; f < FEATD; f++) h += in[f] * sW1[f * HIDD + j];
        h = fmaxf(h, 0.f);
#pragma unroll
        for (int c = 0; c < FEATD; c++) out[c] += h * sW2[j * FEATD + c];
    }
    float dn = dinv[n];
    union { float4 f4; __half2 h2[4]; } o0, o1;
#pragma unroll
    for (int q = 0; q < 4; q++) {
        o0.h2[q] = __floats2half2_rn(out[q * 2] * dn, out[q * 2 + 1] * dn);
        o1.h2[q] = __floats2half2_rn(out[8 + q * 2] * dn, out[8 + q * 2 + 1] * dn);
    }
    ((float4*)(xsH + (size_t)n * 8))[0] = o0.f4;
    ((float4*)(xsH + (size_t)n * 8))[1] = o1.f4;
}

// ---- LSTM input GEMM: 16-row x 128-col tiles, grid 128x8 = 1024 blocks ----
// 4 blocks/CU (16 waves/CU); stride-34 LDS pad -> <=2-way conflicts (free).
#define KT 32
__global__ void __launch_bounds__(256)
k_gemmA(const __half2* __restrict__ h2H, const float* __restrict__ Wih,
        float* __restrict__ gxp) {
    __shared__ float As[16][KT + 2];
    __shared__ float Bs[128][KT + 2];
    int tid = threadIdx.x;
    int row0 = blockIdx.x * 16;
    int k0 = blockIdx.y * (ROWD / KCHUNKS);   // 256-wide K chunk
    int lrow = tid & 15;          // compute row
    int cb = (tid >> 4) * 8;      // col base 0..120
    float acc[8];
#pragma unroll
    for (int j = 0; j < 8; j++) acc[j] = 0.f;
    const __half* h2 = (const __half*)h2H;
    for (int kk = 0; kk < ROWD / KCHUNKS; kk += KT) {
        if (tid < 64) {   // A tile: 16 x 32 halfs, 64 threads x 8 halfs
            int rr = tid >> 2, cc = (tid & 3) * 8;
            union { float4 f4; __half2 h2v[4]; } a;
            a.f4 = *(const float4*)(h2 + (size_t)(row0 + rr) * ROWD + k0 + kk + cc);
#pragma unroll
            for (int q = 0; q < 4; q++) {
                float2 v = __half22float2(a.h2v[q]);
                As[rr][cc + q * 2 + 0] = v.x;
                As[rr][cc + q * 2 + 1] = v.y;
            }
        }
        for (int l = tid; l < 128 * KT / 4; l += 256) {   // B tile: 128 x 32 f32
            int rr = l >> 3;
            int cc = (l & 7) * 4;
            float4 v = *(const float4*)&Wih[(size_t)rr * ROWD + k0 + kk + cc];
            Bs[rr][cc + 0] = v.x; Bs[rr][cc + 1] = v.y; Bs[rr][cc + 2] = v.z; Bs[rr][cc + 3] = v.w;
        }
        __syncthreads();
#pragma unroll
        for (int k = 0; k < KT; k++) {
            float a = As[lrow][k];
#pragma unroll
            for (int j = 0; j < 8; j++) acc[j] += a * Bs[cb + j][k];
        }
        __syncthreads();
    }
    float* outp = gxp + (size_t)blockIdx.y * (ROWD * 128) + (size_t)(row0 + lrow) * 128 + cb;
    float4 o0 = make_float4(acc[0], acc[1], acc[2], acc[3]);
    float4 o1 = make_float4(acc[4], acc[5], acc[6], acc[7]);
    ((float4*)outp)[0] = o0;
    ((float4*)outp)[1] = o1;
}

// ---- gxp partial-sum prereduce ----
__global__ void k_pre(const float* __restrict__ gxp, float* __restrict__ sgx) {
    int i = blockIdx.x * blockDim.x + threadIdx.x;   // ROWD*128 lanes
    if (i >= ROWD * 128) return;
    float s = 0.f;
#pragma unroll
    for (int p = 0; p < KCHUNKS; p++) s += gxp[(size_t)p * ROWD * 128 + i];
    sgx[i] = s;
}

// ---- LSTM recurrence (reads pre-summed sgx) ----
__global__ void k_lstm(const float* __restrict__ sgx, const float* __restrict__ Whh,
                       const float* __restrict__ bih, const float* __restrict__ bhh,
                       float* __restrict__ hseq) {
    __shared__ float sWhhT[LSTMH][4 * LSTMH];   // [k][j] = Whh[j][k]
    __shared__ float sgxL[WIN * 4 * LSTMH];      // 16 KB
    __shared__ float sh[LSTMH], sc[LSTMH], sg[4 * LSTMH];
    int b = blockIdx.x, j = threadIdx.x;
    for (int l = j; l < 4 * LSTMH * LSTMH; l += 4 * LSTMH) {
        int r = l >> 5, k = l & 31;
        sWhhT[k][r] = Whh[l];
    }
    for (int l = j; l < WIN * 128; l += 128) sgxL[l] = sgx[(size_t)b * WIN * 128 + l];
    float bias = bih[j] + bhh[j];
    if (j < LSTMH) { sh[j] = 0.f; sc[j] = 0.f; }
    __syncthreads();
    for (int t = 0; t < WIN; t++) {
        float g = bias + sgxL[t * 128 + j];
#pragma unroll
        for (int k = 0; k < LSTMH; k++) g += sWhhT[k][j] * sh[k];
        sg[j] = g;
        __syncthreads();
        if (j < LSTMH) {
            float ig = sg[j], fg = sg[32 + j], gg = sg[64 + j], og = sg[96 + j];
            float c = sc[j];
            float si = 1.f / (1.f + __expf(-ig));
            float sf = 1.f / (1.f + __expf(-fg));
            float so = 1.f / (1.f + __expf(-og));
            c = sf * c + si * tanhf(gg);
            float h = so * tanhf(c);
            sc[j] = c; sh[j] = h;
            if (t >= WIN - WOUT)
                hseq[(size_t)(b * WOUT + (t - (WIN - WOUT))) * LSTMH + j] = h;
        }
        __syncthreads();
    }
}

// ---- FC head: (512 rows) 32 -> 16 relu -> 10 ----
__global__ void k_fc(const float* __restrict__ hseq, const float* __restrict__ Wfc1,
                     const float* __restrict__ bfc1, const float* __restrict__ Wfc2,
                     const float* __restrict__ bfc2, float* __restrict__ out) {
    __shared__ float sW1[16 * 32], sb1[16], sW2[10 * 16], sb2[10];
    int tid = threadIdx.x;
    for (int l = tid; l < 16 * 32; l += blockDim.x) sW1[l] = Wfc1[l];
    if (tid < 16) sb1[tid] = bfc1[tid];
    for (int l = tid; l < 160; l += blockDim.x) sW2[l] = Wfc2[l];
    if (tid < 10) sb2[tid] = bfc2[tid];
    __syncthreads();
    int r = blockIdx.x * blockDim.x + tid;
    if (r >= BATCH * WOUT) return;
    float h[32];
#pragma unroll
    for (int k = 0; k < 32; k++) h[k] = hseq[(size_t)r * 32 + k];
    float hid[16];
#pragma unroll
    for (int j = 0; j < 16; j++) {
        float v = sb1[j];
#pragma unroll
        for (int k = 0; k < 32; k++) v += sW1[j * 32 + k] * h[k];
        hid[j] = fmaxf(v, 0.f);
    }
#pragma unroll
    for (int c = 0; c < NCLS; c++) {
        float v = sb2[c];
#pragma unroll
        for (int j = 0; j < 16; j++) v += sW2[c * 16 + j] * hid[j];
        out[(size_t)r * NCLS + c] = v;
    }
}

extern "C" void kernel_launch(void* const* d_in, const int* in_sizes, int n_in,
                              void* d_out, int out_size, void* d_ws, size_t ws_size,
                              hipStream_t stream) {
    const float* x    = (const float*)d_in[0];
    const int*   ei   = (const int*)d_in[1];
    const float* W1   = (const float*)d_in[2];
    const float* b1   = (const float*)d_in[3];
    const float* W2   = (const float*)d_in[4];
    const float* b2   = (const float*)d_in[5];
    const float* Wih  = (const float*)d_in[6];
    const float* Whh  = (const float*)d_in[7];
    const float* bih  = (const float*)d_in[8];
    const float* bhh  = (const float*)d_in[9];
    const float* Wfc1 = (const float*)d_in[10];
    const float* bfc1 = (const float*)d_in[11];
    const float* Wfc2 = (const float*)d_in[12];
    const float* bfc2 = (const float*)d_in[13];
    float* out = (float*)d_out;

    float*   ws     = (float*)d_ws;
    float*   dinv   = ws;                                    // NN f32 (1 MB)
    int*     hist2d = (int*)(dinv + NN);                     // NB2*NBLK ints (0.5 MB)
    int*     bcnt   = hist2d + NB2 * NBLK;                   // NB2 ints
    int*     off    = bcnt + NB2;                            // NN ints (1 MB)
    int*     rows   = off + NN;                              // NB2*CAPB ints (9.4 MB)
    __half2* aggH   = (__half2*)(rows + (size_t)NB2 * CAPB); // NN*8 half2 (8 MB)
    __half2* xsH    = aggH + (size_t)NN * 8;                 // NN*8 half2 (8 MB)
    int*     bdata  = (int*)(xsH + (size_t)NN * 8);          // NB2*CAPB ints (9.4 MB)
    float*   gxp    = (float*)bdata;                         // 8 MB, aliases bdata (dead after csrsort)
    float*   sgx    = (float*)(bdata + (size_t)NB2 * CAPB);  // 1 MB
    float*   hseq   = sgx + ROWD * 128;                      // 64 KB

    k_hist<<<NBLK, 256, 0, stream>>>(ei, hist2d);
    k_scan2<<<NB2, NBLK, 0, stream>>>(hist2d, bcnt);
    k_place<<<NBLK, 256, 0, stream>>>(ei, hist2d, bdata);
    k_csrsort<<<NB2, 256, 0, stream>>>(bcnt, bdata, rows, off, dinv);
    k_scale<<<NN * 8 / 256, 256, 0, stream>>>(x, dinv, xsH);

    k_aggcsr<1><<<NN * 8 / 256, 256, 0, stream>>>(rows, off, dinv, xsH, b2, aggH);  // in1
    k_gcnmlp<<<NN / 256, 256, 0, stream>>>(aggH, xsH, dinv, W1, b1, W2);            // t2s
    k_aggcsr<2><<<NN * 8 / 256, 256, 0, stream>>>(rows, off, dinv, xsH, b2, aggH);  // h2

    dim3 gg(ROWD / 16, KCHUNKS);
    k_gemmA<<<gg, 256, 0, stream>>>(aggH, Wih, gxp);
    k_pre<<<ROWD * 128 / 256, 256, 0, stream>>>(gxp, sgx);
    k_lstm<<<BATCH, 128, 0, stream>>>(sgx, Whh, bih, bhh, hseq);
    k_fc<<<2, 256, 0, stream>>>(hseq, Wfc1, bfc1, Wfc2, bfc2, out);
}

// Round 20
// 254.403 us; speedup vs baseline: 2.4189x; 1.0357x over previous
//
#include <hip/hip_runtime.h>
#include <hip/hip_fp16.h>

#define NN      262144    // N = B*WIN_IN*NODES
#define EDGES   2097152
#define FEATD   16
#define HIDD    64
#define LSTMH   32
#define BATCH   64
#define WIN     32
#define WOUT    8
#define NCLS    10
#define ROWD    2048      // NODES*FEAT = B*WIN (both 2048)
#define KCHUNKS 16

#define NB2     512       // dest buckets: c >> 9 (512 nodes each)
#define NW      512       // nodes per bucket
#define CAPB    4608      // per-bucket capacity: Poisson(4096)+8 sigma
#define NBLK    256       // edge chunks
#define CHUNK   (EDGES / NBLK)   // 8192 edges per chunk

// ---- phase 1: per-(block,bucket) histogram ----
__global__ void k_hist(const int* __restrict__ ei, int* __restrict__ hist2d) {
    __shared__ int h[NB2];
    int blk = blockIdx.x, tid = threadIdx.x;
    for (int l = tid; l < NB2; l += 256) h[l] = 0;
    __syncthreads();
    int e0 = blk * CHUNK;
    for (int i = tid; i < CHUNK; i += 256)
        atomicAdd(&h[ei[EDGES + e0 + i] >> 9], 1);
    __syncthreads();
    for (int l = tid; l < NB2; l += 256) hist2d[l * NBLK + blk] = h[l];
}

// ---- phase 2: per-bucket exclusive scan over block counts; totals -> bcnt ----
__global__ void k_scan2(int* __restrict__ hist2d, int* __restrict__ bcnt) {
    __shared__ int s[NBLK];
    int b = blockIdx.x, tid = threadIdx.x;
    int v = hist2d[b * NBLK + tid];
    s[tid] = v;
    __syncthreads();
    for (int off = 1; off < NBLK; off <<= 1) {
        int t = (tid >= off) ? s[tid - off] : 0;
        __syncthreads();
        s[tid] += t;
        __syncthreads();
    }
    hist2d[b * NBLK + tid] = s[tid] - v;   // exclusive base for (bucket, block)
    if (tid == NBLK - 1) bcnt[b] = s[tid];
}

// ---- phase 3: place edges into block-private contiguous runs (full lines) ----
__global__ void k_place(const int* __restrict__ ei, const int* __restrict__ hist2d,
                        int* __restrict__ bdata) {
    __shared__ int curp[NB2];
    int blk = blockIdx.x, tid = threadIdx.x;
    for (int l = tid; l < NB2; l += 256) curp[l] = hist2d[l * NBLK + blk];
    __syncthreads();
    int e0 = blk * CHUNK;
    for (int i = tid; i < CHUNK; i += 256) {
        int r = ei[e0 + i];
        int c = ei[EDGES + e0 + i];
        int b = c >> 9;
        int p = atomicAdd(&curp[b], 1);
        if (p < CAPB) bdata[(size_t)b * CAPB + p] = (r << 9) | (c & 511);
    }
}

// ---- per-bucket LDS counting sort -> dest-sorted rows, offsets, degrees ----
__global__ void __launch_bounds__(256)
k_csrsort(const int* __restrict__ bcnt, const int* __restrict__ bdata,
          int* __restrict__ rows, int* __restrict__ off, float* __restrict__ dinv) {
    __shared__ int sidx[CAPB];          // 18.4 KB
    __shared__ int hist[NW], curp[NW];  // 4 KB
    int b = blockIdx.x, tid = threadIdx.x;
    int total = bcnt[b]; if (total > CAPB) total = CAPB;
    for (int l = tid; l < NW; l += 256) hist[l] = 0;
    __syncthreads();
    const int* base = bdata + (size_t)b * CAPB;
    for (int i = tid; i < total; i += 256) {
        int w = base[i];
        sidx[i] = w;
        atomicAdd(&hist[w & 511], 1);
    }
    __syncthreads();
    if (tid == 0) {
        int run = 0;
        for (int co = 0; co < NW; co++) { curp[co] = run; run += hist[co]; }
    }
    __syncthreads();
    for (int l = tid; l < NW; l += 256) {
        off[b * NW + l] = curp[l] + hist[l];                 // exclusive end
        dinv[b * NW + l] = rsqrtf((float)hist[l] + 1.0f);    // degree byproduct
    }
    __syncthreads();
    for (int i = tid; i < total; i += 256) {
        int w = sidx[i];
        int pos = atomicAdd(&curp[w & 511], 1);
        rows[(size_t)b * CAPB + pos] = w >> 9;               // block-local 18KB window
    }
}

// ---- pre-scale: xsH[n][f2] = half2(x[n]*dinv[n]) ----
__global__ void k_scale(const float* __restrict__ x, const float* __restrict__ dinv,
                        __half2* __restrict__ xsH) {
    int i = blockIdx.x * blockDim.x + threadIdx.x;   // NN*8 half2 lanes
    if (i >= NN * 8) return;
    float d = dinv[i >> 3];
    float2 v = ((const float2*)x)[i];
    xsH[i] = __floats2half2_rn(v.x * d, v.y * d);
}

// ---- zero-atomic CSR gather-reduce, f32 accumulate, fused self (+b2,relu L2) ----
template<int LAYER>
__global__ void __launch_bounds__(256)
k_aggcsr(const int* __restrict__ rows, const int* __restrict__ off,
         const float* __restrict__ dinv, const __half2* __restrict__ srcH,
         const float* __restrict__ b2, __half2* __restrict__ outH) {
    int i = blockIdx.x * blockDim.x + threadIdx.x;
    if (i >= NN * 8) return;
    int n = i >> 3, f2 = i & 7;
    int begin = (n & 511) ? off[n - 1] : 0;
    int end = off[n];
    const size_t base = (size_t)(n >> 9) * CAPB;
    float2 selfv = __half22float2(srcH[(size_t)n * 8 + f2]);
    float ax = selfv.x, ay = selfv.y;
    for (size_t e = base + begin; e < base + end; ++e) {
        int r = rows[e];
        float2 v = __half22float2(srcH[(size_t)r * 8 + f2]);
        ax += v.x; ay += v.y;
    }
    float d = dinv[n];
    ax *= d; ay *= d;
    if (LAYER == 2) {
        ax = fmaxf(ax + b2[f2 * 2 + 0], 0.f);
        ay = fmaxf(ay + b2[f2 * 2 + 1], 0.f);
    }
    outH[i] = __floats2half2_rn(ax, ay);
}

// ---- fused MLP: hid = relu(in1@W1+b1) ; t2s = (hid@W2)*dinv -> fp16 over xsH ----
__global__ void k_gcnmlp(const __half2* __restrict__ in1H, __half2* __restrict__ xsH,
                         const float* __restrict__ dinv,
                         const float* __restrict__ W1, const float* __restrict__ b1,
                         const float* __restrict__ W2) {
    __shared__ float sW1[FEATD * HIDD];
    __shared__ float sW2[HIDD * FEATD];
    __shared__ float sb1[HIDD];
    for (int l = threadIdx.x; l < FEATD * HIDD; l += blockDim.x) {
        sW1[l] = W1[l];
        sW2[l] = W2[l];
    }
    if (threadIdx.x < HIDD) sb1[threadIdx.x] = b1[threadIdx.x];
    __syncthreads();
    int n = blockIdx.x * blockDim.x + threadIdx.x;
    if (n >= NN) return;
    union { float4 f4; __half2 h2[4]; } a0, a1;
    a0.f4 = ((const float4*)(in1H + (size_t)n * 8))[0];
    a1.f4 = ((const float4*)(in1H + (size_t)n * 8))[1];
    float in[FEATD];
#pragma unroll
    for (int q = 0; q < 4; q++) {
        float2 v = __half22float2(a0.h2[q]);
        in[q * 2 + 0] = v.x; in[q * 2 + 1] = v.y;
        v = __half22float2(a1.h2[q]);
        in[8 + q * 2 + 0] = v.x; in[8 + q * 2 + 1] = v.y;
    }
    float out[FEATD];
#pragma unroll
    for (int c = 0; c < FEATD; c++) out[c] = 0.f;
#pragma unroll 8
    for (int j = 0; j < HIDD; j++) {
        float h = sb1[j];
#pragma unroll
        for (int f = 0; f < FEATD; f++) h += in[f] * sW1[f * HIDD + j];
        h = fmaxf(h, 0.f);
#pragma unroll
        for (int c = 0; c < FEATD; c++) out[c] += h * sW2[j * FEATD + c];
    }
    float dn = dinv[n];
    union { float4 f4; __half2 h2[4]; } o0, o1;
#pragma unroll
    for (int q = 0; q < 4; q++) {
        o0.h2[q] = __floats2half2_rn(out[q * 2] * dn, out[q * 2 + 1] * dn);
        o1.h2[q] = __floats2half2_rn(out[8 + q * 2] * dn, out[8 + q * 2 + 1] * dn);
    }
    ((float4*)(xsH + (size_t)n * 8))[0] = o0.f4;
    ((float4*)(xsH + (size_t)n * 8))[1] = o1.f4;
}

// ---- LSTM input GEMM: 16-row x 128-col tiles, K split x16 ----
// B stored k-major (Bs[k][col], pad 132): per k = 1 broadcast b32 + 2 b128
// reads, conflict-free. grid 128x16 = 2048 blocks = 8/CU.
#define KT 32
#define KSPAN (ROWD / KCHUNKS)   // 128
__global__ void __launch_bounds__(256)
k_gemmA(const __half2* __restrict__ h2H, const float* __restrict__ Wih,
        float* __restrict__ gxp) {
    __shared__ float As[16][KT + 2];      // 2.2 KB
    __shared__ float Bs[KT][128 + 4];     // 16.9 KB
    int tid = threadIdx.x;
    int row0 = blockIdx.x * 16;
    int k0 = blockIdx.y * KSPAN;
    int lrow = tid & 15;          // compute row
    int cb = (tid >> 4) * 8;      // col base 0..120
    float acc[8];
#pragma unroll
    for (int j = 0; j < 8; j++) acc[j] = 0.f;
    const __half* h2 = (const __half*)h2H;
    for (int kk = 0; kk < KSPAN; kk += KT) {
        if (tid < 64) {   // A tile: 16 x 32 halfs, 64 threads x 8 halfs
            int rr = tid >> 2, cc = (tid & 3) * 8;
            union { float4 f4; __half2 h2v[4]; } a;
            a.f4 = *(const float4*)(h2 + (size_t)(row0 + rr) * ROWD + k0 + kk + cc);
#pragma unroll
            for (int q = 0; q < 4; q++) {
                float2 v = __half22float2(a.h2v[q]);
                As[rr][cc + q * 2 + 0] = v.x;
                As[rr][cc + q * 2 + 1] = v.y;
            }
        }
        // B tile transposed store: 128 rows x 32 k -> Bs[k][col]
#pragma unroll
        for (int w = 0; w < 4; w++) {
            int idx = tid + w * 256;          // 0..1023
            int rr = idx >> 3;                // Wih row (col of B)
            int cc = (idx & 7) * 4;           // k offset
            float4 v = *(const float4*)&Wih[(size_t)rr * ROWD + k0 + kk + cc];
            Bs[cc + 0][rr] = v.x;
            Bs[cc + 1][rr] = v.y;
            Bs[cc + 2][rr] = v.z;
            Bs[cc + 3][rr] = v.w;
        }
        __syncthreads();
#pragma unroll
        for (int k = 0; k < KT; k++) {
            float a = As[lrow][k];
            float4 b0 = *(const float4*)&Bs[k][cb];
            float4 b1 = *(const float4*)&Bs[k][cb + 4];
            acc[0] += a * b0.x; acc[1] += a * b0.y;
            acc[2] += a * b0.z; acc[3] += a * b0.w;
            acc[4] += a * b1.x; acc[5] += a * b1.y;
            acc[6] += a * b1.z; acc[7] += a * b1.w;
        }
        __syncthreads();
    }
    float* outp = gxp + (size_t)blockIdx.y * (ROWD * 128) + (size_t)(row0 + lrow) * 128 + cb;
    ((float4*)outp)[0] = make_float4(acc[0], acc[1], acc[2], acc[3]);
    ((float4*)outp)[1] = make_float4(acc[4], acc[5], acc[6], acc[7]);
}

// ---- gxp partial-sum prereduce ----
__global__ void k_pre(const float* __restrict__ gxp, float* __restrict__ sgx) {
    int i = blockIdx.x * blockDim.x + threadIdx.x;   // ROWD*128 lanes
    if (i >= ROWD * 128) return;
    float s = 0.f;
#pragma unroll
    for (int p = 0; p < KCHUNKS; p++) s += gxp[(size_t)p * ROWD * 128 + i];
    sgx[i] = s;
}

// ---- LSTM recurrence (reads pre-summed sgx) ----
__global__ void k_lstm(const float* __restrict__ sgx, const float* __restrict__ Whh,
                       const float* __restrict__ bih, const float* __restrict__ bhh,
                       float* __restrict__ hseq) {
    __shared__ float sWhhT[LSTMH][4 * LSTMH];   // [k][j] = Whh[j][k]
    __shared__ float sgxL[WIN * 4 * LSTMH];      // 16 KB
    __shared__ float sh[LSTMH], sc[LSTMH], sg[4 * LSTMH];
    int b = blockIdx.x, j = threadIdx.x;
    for (int l = j; l < 4 * LSTMH * LSTMH; l += 4 * LSTMH) {
        int r = l >> 5, k = l & 31;
        sWhhT[k][r] = Whh[l];
    }
    for (int l = j; l < WIN * 128; l += 128) sgxL[l] = sgx[(size_t)b * WIN * 128 + l];
    float bias = bih[j] + bhh[j];
    if (j < LSTMH) { sh[j] = 0.f; sc[j] = 0.f; }
    __syncthreads();
    for (int t = 0; t < WIN; t++) {
        float g = bias + sgxL[t * 128 + j];
#pragma unroll
        for (int k = 0; k < LSTMH; k++) g += sWhhT[k][j] * sh[k];
        sg[j] = g;
        __syncthreads();
        if (j < LSTMH) {
            float ig = sg[j], fg = sg[32 + j], gg = sg[64 + j], og = sg[96 + j];
            float c = sc[j];
            float si = 1.f / (1.f + __expf(-ig));
            float sf = 1.f / (1.f + __expf(-fg));
            float so = 1.f / (1.f + __expf(-og));
            c = sf * c + si * tanhf(gg);
            float h = so * tanhf(c);
            sc[j] = c; sh[j] = h;
            if (t >= WIN - WOUT)
                hseq[(size_t)(b * WOUT + (t - (WIN - WOUT))) * LSTMH + j] = h;
        }
        __syncthreads();
    }
}

// ---- FC head: (512 rows) 32 -> 16 relu -> 10 ----
__global__ void k_fc(const float* __restrict__ hseq, const float* __restrict__ Wfc1,
                     const float* __restrict__ bfc1, const float* __restrict__ Wfc2,
                     const float* __restrict__ bfc2, float* __restrict__ out) {
    __shared__ float sW1[16 * 32], sb1[16], sW2[10 * 16], sb2[10];
    int tid = threadIdx.x;
    for (int l = tid; l < 16 * 32; l += blockDim.x) sW1[l] = Wfc1[l];
    if (tid < 16) sb1[tid] = bfc1[tid];
    for (int l = tid; l < 160; l += blockDim.x) sW2[l] = Wfc2[l];
    if (tid < 10) sb2[tid] = bfc2[tid];
    __syncthreads();
    int r = blockIdx.x * blockDim.x + tid;
    if (r >= BATCH * WOUT) return;
    float h[32];
#pragma unroll
    for (int k = 0; k < 32; k++) h[k] = hseq[(size_t)r * 32 + k];
    float hid[16];
#pragma unroll
    for (int j = 0; j < 16; j++) {
        float v = sb1[j];
#pragma unroll
        for (int k = 0; k < 32; k++) v += sW1[j * 32 + k] * h[k];
        hid[j] = fmaxf(v, 0.f);
    }
#pragma unroll
    for (int c = 0; c < NCLS; c++) {
        float v = sb2[c];
#pragma unroll
        for (int j = 0; j < 16; j++) v += sW2[c * 16 + j] * hid[j];
        out[(size_t)r * NCLS + c] = v;
    }
}

extern "C" void kernel_launch(void* const* d_in, const int* in_sizes, int n_in,
                              void* d_out, int out_size, void* d_ws, size_t ws_size,
                              hipStream_t stream) {
    const float* x    = (const float*)d_in[0];
    const int*   ei   = (const int*)d_in[1];
    const float* W1   = (const float*)d_in[2];
    const float* b1   = (const float*)d_in[3];
    const float* W2   = (const float*)d_in[4];
    const float* b2   = (const float*)d_in[5];
    const float* Wih  = (const float*)d_in[6];
    const float* Whh  = (const float*)d_in[7];
    const float* bih  = (const float*)d_in[8];
    const float* bhh  = (const float*)d_in[9];
    const float* Wfc1 = (const float*)d_in[10];
    const float* bfc1 = (const float*)d_in[11];
    const float* Wfc2 = (const float*)d_in[12];
    const float* bfc2 = (const float*)d_in[13];
    float* out = (float*)d_out;

    float*   ws     = (float*)d_ws;
    float*   dinv   = ws;                                    // NN f32 (1 MB)
    int*     hist2d = (int*)(dinv + NN);                     // NB2*NBLK ints (0.5 MB)
    int*     bcnt   = hist2d + NB2 * NBLK;                   // NB2 ints
    int*     off    = bcnt + NB2;                            // NN ints (1 MB)
    int*     rows   = off + NN;                              // NB2*CAPB ints (9.4 MB)
    __half2* aggH   = (__half2*)(rows + (size_t)NB2 * CAPB); // NN*8 half2 (8 MB)
    __half2* xsH    = aggH + (size_t)NN * 8;                 // NN*8 half2 (8 MB)
    int*     bdata  = (int*)(xsH + (size_t)NN * 8);          // NB2*CAPB ints (9.4 MB)
    float*   gxp    = (float*)(bdata + (size_t)NB2 * CAPB);  // KCHUNKS*2048*128 f32 (16 MB)
    float*   sgx    = gxp + (size_t)KCHUNKS * ROWD * 128;    // 1 MB
    float*   hseq   = sgx + ROWD * 128;                      // 64 KB

    k_hist<<<NBLK, 256, 0, stream>>>(ei, hist2d);
    k_scan2<<<NB2, NBLK, 0, stream>>>(hist2d, bcnt);
    k_place<<<NBLK, 256, 0, stream>>>(ei, hist2d, bdata);
    k_csrsort<<<NB2, 256, 0, stream>>>(bcnt, bdata, rows, off, dinv);
    k_scale<<<NN * 8 / 256, 256, 0, stream>>>(x, dinv, xsH);

    k_aggcsr<1><<<NN * 8 / 256, 256, 0, stream>>>(rows, off, dinv, xsH, b2, aggH);  // in1
    k_gcnmlp<<<NN / 256, 256, 0, stream>>>(aggH, xsH, dinv, W1, b1, W2);            // t2s
    k_aggcsr<2><<<NN * 8 / 256, 256, 0, stream>>>(rows, off, dinv, xsH, b2, aggH);  // h2

    dim3 gg(ROWD / 16, KCHUNKS);
    k_gemmA<<<gg, 256, 0, stream>>>(aggH, Wih, gxp);
    k_pre<<<ROWD * 128 / 256, 256, 0, stream>>>(gxp, sgx);
    k_lstm<<<BATCH, 128, 0, stream>>>(sgx, Whh, bih, bhh, hseq);
    k_fc<<<2, 256, 0, stream>>>(hseq, Wfc1, bfc1, Wfc2, bfc2, out);
}

// Round 21
// 235.299 us; speedup vs baseline: 2.6153x; 1.0812x over previous
//
#include <hip/hip_runtime.h>
#include <hip/hip_fp16.h>

#define NN      262144    // N = B*WIN_IN*NODES
#define EDGES   2097152
#define FEATD   16
#define HIDD    64
#define LSTMH   32
#define BATCH   64
#define WIN     32
#define WOUT    8
#define NCLS    10
#define ROWD    2048      // NODES*FEAT = B*WIN (both 2048)
#define KCHUNKS 16

#define NB2     512       // dest buckets: c >> 9 (512 nodes each)
#define NW      512       // nodes per bucket
#define CAPB    4608      // per-bucket capacity: Poisson(4096)+8 sigma
#define NBLK    256       // edge chunks
#define CHUNK   (EDGES / NBLK)   // 8192 edges per chunk

// ---- phase 1: per-(block,bucket) histogram ----
__global__ void k_hist(const int* __restrict__ ei, int* __restrict__ hist2d) {
    __shared__ int h[NB2];
    int blk = blockIdx.x, tid = threadIdx.x;
    for (int l = tid; l < NB2; l += 256) h[l] = 0;
    __syncthreads();
    int e0 = blk * CHUNK;
    for (int i = tid; i < CHUNK; i += 256)
        atomicAdd(&h[ei[EDGES + e0 + i] >> 9], 1);
    __syncthreads();
    for (int l = tid; l < NB2; l += 256) hist2d[l * NBLK + blk] = h[l];
}

// ---- phase 2: per-bucket exclusive scan over block counts; totals -> bcnt ----
__global__ void k_scan2(int* __restrict__ hist2d, int* __restrict__ bcnt) {
    __shared__ int s[NBLK];
    int b = blockIdx.x, tid = threadIdx.x;
    int v = hist2d[b * NBLK + tid];
    s[tid] = v;
    __syncthreads();
    for (int off = 1; off < NBLK; off <<= 1) {
        int t = (tid >= off) ? s[tid - off] : 0;
        __syncthreads();
        s[tid] += t;
        __syncthreads();
    }
    hist2d[b * NBLK + tid] = s[tid] - v;   // exclusive base for (bucket, block)
    if (tid == NBLK - 1) bcnt[b] = s[tid];
}

// ---- phase 3: place edges into block-private contiguous runs (full lines) ----
__global__ void k_place(const int* __restrict__ ei, const int* __restrict__ hist2d,
                        int* __restrict__ bdata) {
    __shared__ int curp[NB2];
    int blk = blockIdx.x, tid = threadIdx.x;
    for (int l = tid; l < NB2; l += 256) curp[l] = hist2d[l * NBLK + blk];
    __syncthreads();
    int e0 = blk * CHUNK;
    for (int i = tid; i < CHUNK; i += 256) {
        int r = ei[e0 + i];
        int c = ei[EDGES + e0 + i];
        int b = c >> 9;
        int p = atomicAdd(&curp[b], 1);
        if (p < CAPB) bdata[(size_t)b * CAPB + p] = (r << 9) | (c & 511);
    }
}

// ---- per-bucket LDS counting sort (512 threads, parallel scan) ----
__global__ void __launch_bounds__(512)
k_csrsort(const int* __restrict__ bcnt, const int* __restrict__ bdata,
          int* __restrict__ rows, int* __restrict__ offp, float* __restrict__ dinv) {
    __shared__ int sidx[CAPB];          // 18.4 KB
    __shared__ int sorted[CAPB];        // 18.4 KB
    __shared__ int hist[NW], curp[NW], ssc[NW];
    int b = blockIdx.x, tid = threadIdx.x;
    int total = bcnt[b]; if (total > CAPB) total = CAPB;
    hist[tid] = 0;
    __syncthreads();
    const int* base = bdata + (size_t)b * CAPB;
    for (int i = tid; i < total; i += 512) {
        int w = base[i];
        sidx[i] = w;
        atomicAdd(&hist[w & 511], 1);
    }
    __syncthreads();
    int v = hist[tid];
    ssc[tid] = v;
    __syncthreads();
    for (int st = 1; st < NW; st <<= 1) {
        int t = (tid >= st) ? ssc[tid - st] : 0;
        __syncthreads();
        ssc[tid] += t;
        __syncthreads();
    }
    curp[tid] = ssc[tid] - v;                       // exclusive start
    offp[b * NW + tid] = ssc[tid];                  // inclusive end
    dinv[b * NW + tid] = rsqrtf((float)v + 1.0f);   // degree byproduct
    __syncthreads();
    for (int i = tid; i < total; i += 512) {
        int w = sidx[i];
        int pos = atomicAdd(&curp[w & 511], 1);
        sorted[pos] = w >> 9;
    }
    __syncthreads();
    for (int i = tid; i < total; i += 512) rows[(size_t)b * CAPB + i] = sorted[i];
}

// ---- pre-scale: xsH[n][f2] = half2(x[n]*dinv[n]) ----
__global__ void k_scale(const float* __restrict__ x, const float* __restrict__ dinv,
                        __half2* __restrict__ xsH) {
    int i = blockIdx.x * blockDim.x + threadIdx.x;   // NN*8 half2 lanes
    if (i >= NN * 8) return;
    float d = dinv[i >> 3];
    float2 v = ((const float2*)x)[i];
    xsH[i] = __floats2half2_rn(v.x * d, v.y * d);
}

// ---- zero-atomic CSR gather-reduce, f32 accumulate, fused self (+b2,relu L2) ----
template<int LAYER>
__global__ void __launch_bounds__(256)
k_aggcsr(const int* __restrict__ rows, const int* __restrict__ off,
         const float* __restrict__ dinv, const __half2* __restrict__ srcH,
         const float* __restrict__ b2, __half2* __restrict__ outH) {
    int i = blockIdx.x * blockDim.x + threadIdx.x;
    if (i >= NN * 8) return;
    int n = i >> 3, f2 = i & 7;
    int begin = (n & 511) ? off[n - 1] : 0;
    int end = off[n];
    const size_t base = (size_t)(n >> 9) * CAPB;
    float2 selfv = __half22float2(srcH[(size_t)n * 8 + f2]);
    float ax = selfv.x, ay = selfv.y;
    for (size_t e = base + begin; e < base + end; ++e) {
        int r = rows[e];
        float2 v = __half22float2(srcH[(size_t)r * 8 + f2]);
        ax += v.x; ay += v.y;
    }
    float d = dinv[n];
    ax *= d; ay *= d;
    if (LAYER == 2) {
        ax = fmaxf(ax + b2[f2 * 2 + 0], 0.f);
        ay = fmaxf(ay + b2[f2 * 2 + 1], 0.f);
    }
    outH[i] = __floats2half2_rn(ax, ay);
}

// ---- fused MLP: hid = relu(in1@W1+b1) ; t2s = (hid@W2)*dinv -> fp16 over xsH ----
__global__ void k_gcnmlp(const __half2* __restrict__ in1H, __half2* __restrict__ xsH,
                         const float* __restrict__ dinv,
                         const float* __restrict__ W1, const float* __restrict__ b1,
                         const float* __restrict__ W2) {
    __shared__ float sW1[FEATD * HIDD];
    __shared__ float sW2[HIDD * FEATD];
    __shared__ float sb1[HIDD];
    for (int l = threadIdx.x; l < FEATD * HIDD; l += blockDim.x) {
        sW1[l] = W1[l];
        sW2[l] = W2[l];
    }
    if (threadIdx.x < HIDD) sb1[threadIdx.x] = b1[threadIdx.x];
    __syncthreads();
    int n = blockIdx.x * blockDim.x + threadIdx.x;
    if (n >= NN) return;
    union { float4 f4; __half2 h2[4]; } a0, a1;
    a0.f4 = ((const float4*)(in1H + (size_t)n * 8))[0];
    a1.f4 = ((const float4*)(in1H + (size_t)n * 8))[1];
    float in[FEATD];
#pragma unroll
    for (int q = 0; q < 4; q++) {
        float2 v = __half22float2(a0.h2[q]);
        in[q * 2 + 0] = v.x; in[q * 2 + 1] = v.y;
        v = __half22float2(a1.h2[q]);
        in[8 + q * 2 + 0] = v.x; in[8 + q * 2 + 1] = v.y;
    }
    float out[FEATD];
#pragma unroll
    for (int c = 0; c < FEATD; c++) out[c] = 0.f;
#pragma unroll 8
    for (int j = 0; j < HIDD; j++) {
        float h = sb1[j];
#pragma unroll
        for (int f = 0; f < FEATD; f++) h += in[f] * sW1[f * HIDD + j];
        h = fmaxf(h, 0.f);
#pragma unroll
        for (int c = 0; c < FEATD; c++) out[c] += h * sW2[j * FEATD + c];
    }
    float dn = dinv[n];
    union { float4 f4; __half2 h2[4]; } o0, o1;
#pragma unroll
    for (int q = 0; q < 4; q++) {
        o0.h2[q] = __floats2half2_rn(out[q * 2] * dn, out[q * 2 + 1] * dn);
        o1.h2[q] = __floats2half2_rn(out[8 + q * 2] * dn, out[8 + q * 2 + 1] * dn);
    }
    ((float4*)(xsH + (size_t)n * 8))[0] = o0.f4;
    ((float4*)(xsH + (size_t)n * 8))[1] = o1.f4;
}

// ---- LSTM input GEMM: 32-row x 128-col tiles, 2 rows/thread, K split x16 ----
// Per k: 2 broadcast b32 + 2 b128 feed 16 FMAs (FMA/LDS balanced).
#define KT 32
#define KSPAN (ROWD / KCHUNKS)   // 128
__global__ void __launch_bounds__(256)
k_gemmA(const __half2* __restrict__ h2H, const float* __restrict__ Wih,
        float* __restrict__ gxp) {
    __shared__ float As[32][KT + 2];      // 4.3 KB
    __shared__ float Bs[KT][128 + 4];     // 16.9 KB
    int tid = threadIdx.x;
    int row0 = blockIdx.x * 32;
    int k0 = blockIdx.y * KSPAN;
    int r0 = tid & 15, r1 = r0 + 16;
    int cb = (tid >> 4) * 8;      // col base 0..120
    float acc0[8], acc1[8];
#pragma unroll
    for (int j = 0; j < 8; j++) { acc0[j] = 0.f; acc1[j] = 0.f; }
    const __half* h2 = (const __half*)h2H;
    for (int kk = 0; kk < KSPAN; kk += KT) {
        if (tid < 128) {   // A tile: 32 x 32 halfs, 128 threads x 8 halfs
            int rr = tid >> 2, cc = (tid & 3) * 8;
            union { float4 f4; __half2 h2v[4]; } a;
            a.f4 = *(const float4*)(h2 + (size_t)(row0 + rr) * ROWD + k0 + kk + cc);
#pragma unroll
            for (int q = 0; q < 4; q++) {
                float2 v = __half22float2(a.h2v[q]);
                As[rr][cc + q * 2 + 0] = v.x;
                As[rr][cc + q * 2 + 1] = v.y;
            }
        }
        // B tile transposed store: 128 rows x 32 k -> Bs[k][col]
#pragma unroll
        for (int w = 0; w < 4; w++) {
            int idx = tid + w * 256;          // 0..1023
            int rr = idx >> 3;                // Wih row (col of B)
            int cc = (idx & 7) * 4;           // k offset
            float4 v = *(const float4*)&Wih[(size_t)rr * ROWD + k0 + kk + cc];
            Bs[cc + 0][rr] = v.x;
            Bs[cc + 1][rr] = v.y;
            Bs[cc + 2][rr] = v.z;
            Bs[cc + 3][rr] = v.w;
        }
        __syncthreads();
#pragma unroll
        for (int k = 0; k < KT; k++) {
            float a0 = As[r0][k];
            float a1 = As[r1][k];
            float4 b0 = *(const float4*)&Bs[k][cb];
            float4 b1 = *(const float4*)&Bs[k][cb + 4];
            acc0[0] += a0 * b0.x; acc0[1] += a0 * b0.y;
            acc0[2] += a0 * b0.z; acc0[3] += a0 * b0.w;
            acc0[4] += a0 * b1.x; acc0[5] += a0 * b1.y;
            acc0[6] += a0 * b1.z; acc0[7] += a0 * b1.w;
            acc1[0] += a1 * b0.x; acc1[1] += a1 * b0.y;
            acc1[2] += a1 * b0.z; acc1[3] += a1 * b0.w;
            acc1[4] += a1 * b1.x; acc1[5] += a1 * b1.y;
            acc1[6] += a1 * b1.z; acc1[7] += a1 * b1.w;
        }
        __syncthreads();
    }
    float* o0 = gxp + (size_t)blockIdx.y * (ROWD * 128) + (size_t)(row0 + r0) * 128 + cb;
    float* o1 = gxp + (size_t)blockIdx.y * (ROWD * 128) + (size_t)(row0 + r1) * 128 + cb;
    ((float4*)o0)[0] = make_float4(acc0[0], acc0[1], acc0[2], acc0[3]);
    ((float4*)o0)[1] = make_float4(acc0[4], acc0[5], acc0[6], acc0[7]);
    ((float4*)o1)[0] = make_float4(acc1[0], acc1[1], acc1[2], acc1[3]);
    ((float4*)o1)[1] = make_float4(acc1[4], acc1[5], acc1[6], acc1[7]);
}

// ---- gxp partial-sum prereduce ----
__global__ void k_pre(const float* __restrict__ gxp, float* __restrict__ sgx) {
    int i = blockIdx.x * blockDim.x + threadIdx.x;   // ROWD*128 lanes
    if (i >= ROWD * 128) return;
    float s = 0.f;
#pragma unroll
    for (int p = 0; p < KCHUNKS; p++) s += gxp[(size_t)p * ROWD * 128 + i];
    sgx[i] = s;
}

// ---- LSTM recurrence (reads pre-summed sgx) ----
__global__ void k_lstm(const float* __restrict__ sgx, const float* __restrict__ Whh,
                       const float* __restrict__ bih, const float* __restrict__ bhh,
                       float* __restrict__ hseq) {
    __shared__ float sWhhT[LSTMH][4 * LSTMH];   // [k][j] = Whh[j][k]
    __shared__ float sgxL[WIN * 4 * LSTMH];      // 16 KB
    __shared__ float sh[LSTMH], sc[LSTMH], sg[4 * LSTMH];
    int b = blockIdx.x, j = threadIdx.x;
    for (int l = j; l < 4 * LSTMH * LSTMH; l += 4 * LSTMH) {
        int r = l >> 5, k = l & 31;
        sWhhT[k][r] = Whh[l];
    }
    for (int l = j; l < WIN * 128; l += 128) sgxL[l] = sgx[(size_t)b * WIN * 128 + l];
    float bias = bih[j] + bhh[j];
    if (j < LSTMH) { sh[j] = 0.f; sc[j] = 0.f; }
    __syncthreads();
    for (int t = 0; t < WIN; t++) {
        float g = bias + sgxL[t * 128 + j];
#pragma unroll
        for (int k = 0; k < LSTMH; k++) g += sWhhT[k][j] * sh[k];
        sg[j] = g;
        __syncthreads();
        if (j < LSTMH) {
            float ig = sg[j], fg = sg[32 + j], gg = sg[64 + j], og = sg[96 + j];
            float c = sc[j];
            float si = 1.f / (1.f + __expf(-ig));
            float sf = 1.f / (1.f + __expf(-fg));
            float so = 1.f / (1.f + __expf(-og));
            c = sf * c + si * tanhf(gg);
            float h = so * tanhf(c);
            sc[j] = c; sh[j] = h;
            if (t >= WIN - WOUT)
                hseq[(size_t)(b * WOUT + (t - (WIN - WOUT))) * LSTMH + j] = h;
        }
        __syncthreads();
    }
}

// ---- FC head: (512 rows) 32 -> 16 relu -> 10 ----
__global__ void k_fc(const float* __restrict__ hseq, const float* __restrict__ Wfc1,
                     const float* __restrict__ bfc1, const float* __restrict__ Wfc2,
                     const float* __restrict__ bfc2, float* __restrict__ out) {
    __shared__ float sW1[16 * 32], sb1[16], sW2[10 * 16], sb2[10];
    int tid = threadIdx.x;
    for (int l = tid; l < 16 * 32; l += blockDim.x) sW1[l] = Wfc1[l];
    if (tid < 16) sb1[tid] = bfc1[tid];
    for (int l = tid; l < 160; l += blockDim.x) sW2[l] = Wfc2[l];
    if (tid < 10) sb2[tid] = bfc2[tid];
    __syncthreads();
    int r = blockIdx.x * blockDim.x + tid;
    if (r >= BATCH * WOUT) return;
    float h[32];
#pragma unroll
    for (int k = 0; k < 32; k++) h[k] = hseq[(size_t)r * 32 + k];
    float hid[16];
#pragma unroll
    for (int j = 0; j < 16; j++) {
        float v = sb1[j];
#pragma unroll
        for (int k = 0; k < 32; k++) v += sW1[j * 32 + k] * h[k];
        hid[j] = fmaxf(v, 0.f);
    }
#pragma unroll
    for (int c = 0; c < NCLS; c++) {
        float v = sb2[c];
#pragma unroll
        for (int j = 0; j < 16; j++) v += sW2[c * 16 + j] * hid[j];
        out[(size_t)r * NCLS + c] = v;
    }
}

extern "C" void kernel_launch(void* const* d_in, const int* in_sizes, int n_in,
                              void* d_out, int out_size, void* d_ws, size_t ws_size,
                              hipStream_t stream) {
    const float* x    = (const float*)d_in[0];
    const int*   ei   = (const int*)d_in[1];
    const float* W1   = (const float*)d_in[2];
    const float* b1   = (const float*)d_in[3];
    const float* W2   = (const float*)d_in[4];
    const float* b2   = (const float*)d_in[5];
    const float* Wih  = (const float*)d_in[6];
    const float* Whh  = (const float*)d_in[7];
    const float* bih  = (const float*)d_in[8];
    const float* bhh  = (const float*)d_in[9];
    const float* Wfc1 = (const float*)d_in[10];
    const float* bfc1 = (const float*)d_in[11];
    const float* Wfc2 = (const float*)d_in[12];
    const float* bfc2 = (const float*)d_in[13];
    float* out = (float*)d_out;

    float*   ws     = (float*)d_ws;
    float*   dinv   = ws;                                    // NN f32 (1 MB)
    int*     hist2d = (int*)(dinv + NN);                     // NB2*NBLK ints (0.5 MB)
    int*     bcnt   = hist2d + NB2 * NBLK;                   // NB2 ints
    int*     off    = bcnt + NB2;                            // NN ints (1 MB)
    int*     rows   = off + NN;                              // NB2*CAPB ints (9.4 MB)
    __half2* aggH   = (__half2*)(rows + (size_t)NB2 * CAPB); // NN*8 half2 (8 MB)
    __half2* xsH    = aggH + (size_t)NN * 8;                 // NN*8 half2 (8 MB)
    int*     bdata  = (int*)(xsH + (size_t)NN * 8);          // NB2*CAPB ints (9.4 MB)
    float*   gxp    = (float*)(bdata + (size_t)NB2 * CAPB);  // KCHUNKS*2048*128 f32 (16 MB)
    float*   sgx    = gxp + (size_t)KCHUNKS * ROWD * 128;    // 1 MB
    float*   hseq   = sgx + ROWD * 128;                      // 64 KB

    k_hist<<<NBLK, 256, 0, stream>>>(ei, hist2d);
    k_scan2<<<NB2, NBLK, 0, stream>>>(hist2d, bcnt);
    k_place<<<NBLK, 256, 0, stream>>>(ei, hist2d, bdata);
    k_csrsort<<<NB2, 512, 0, stream>>>(bcnt, bdata, rows, off, dinv);
    k_scale<<<NN * 8 / 256, 256, 0, stream>>>(x, dinv, xsH);

    k_aggcsr<1><<<NN * 8 / 256, 256, 0, stream>>>(rows, off, dinv, xsH, b2, aggH);  // in1
    k_gcnmlp<<<NN / 256, 256, 0, stream>>>(aggH, xsH, dinv, W1, b1, W2);            // t2s
    k_aggcsr<2><<<NN * 8 / 256, 256, 0, stream>>>(rows, off, dinv, xsH, b2, aggH);  // h2

    dim3 gg(ROWD / 32, KCHUNKS);
    k_gemmA<<<gg, 256, 0, stream>>>(aggH, Wih, gxp);
    k_pre<<<ROWD * 128 / 256, 256, 0, stream>>>(gxp, sgx);
    k_lstm<<<BATCH, 128, 0, stream>>>(sgx, Whh, bih, bhh, hseq);
    k_fc<<<2, 256, 0, stream>>>(hseq, Wfc1, bfc1, Wfc2, bfc2, out);
}

// Round 22
// 222.420 us; speedup vs baseline: 2.7668x; 1.0579x over previous
//
#include <hip/hip_runtime.h>
#include <hip/hip_fp16.h>

#define NN      262144    // N = B*WIN_IN*NODES
#define EDGES   2097152
#define FEATD   16
#define HIDD    64
#define LSTMH   32
#define BATCH   64
#define WIN     32
#define WOUT    8
#define NCLS    10
#define ROWD    2048      // NODES*FEAT = B*WIN (both 2048)
#define KCHUNKS 16
#define KSPAN   (ROWD / KCHUNKS)   // 128

#define NB2     512       // dest buckets: c >> 9 (512 nodes each)
#define NW      512       // nodes per bucket
#define CAPB    4608      // per-bucket capacity: Poisson(4096)+8 sigma
#define NBLK    256       // edge chunks
#define CHUNK   (EDGES / NBLK)   // 8192 edges per chunk

typedef __fp16 half4v __attribute__((ext_vector_type(4)));
typedef float  float4v __attribute__((ext_vector_type(4)));

// ---- phase 1: per-(block,bucket) histogram ----
__global__ void k_hist(const int* __restrict__ ei, int* __restrict__ hist2d) {
    __shared__ int h[NB2];
    int blk = blockIdx.x, tid = threadIdx.x;
    for (int l = tid; l < NB2; l += 256) h[l] = 0;
    __syncthreads();
    int e0 = blk * CHUNK;
    for (int i = tid; i < CHUNK; i += 256)
        atomicAdd(&h[ei[EDGES + e0 + i] >> 9], 1);
    __syncthreads();
    for (int l = tid; l < NB2; l += 256) hist2d[l * NBLK + blk] = h[l];
}

// ---- phase 2: per-bucket exclusive scan over block counts; totals -> bcnt ----
__global__ void k_scan2(int* __restrict__ hist2d, int* __restrict__ bcnt) {
    __shared__ int s[NBLK];
    int b = blockIdx.x, tid = threadIdx.x;
    int v = hist2d[b * NBLK + tid];
    s[tid] = v;
    __syncthreads();
    for (int off = 1; off < NBLK; off <<= 1) {
        int t = (tid >= off) ? s[tid - off] : 0;
        __syncthreads();
        s[tid] += t;
        __syncthreads();
    }
    hist2d[b * NBLK + tid] = s[tid] - v;   // exclusive base for (bucket, block)
    if (tid == NBLK - 1) bcnt[b] = s[tid];
}

// ---- phase 3: place edges into block-private contiguous runs (full lines) ----
__global__ void k_place(const int* __restrict__ ei, const int* __restrict__ hist2d,
                        int* __restrict__ bdata) {
    __shared__ int curp[NB2];
    int blk = blockIdx.x, tid = threadIdx.x;
    for (int l = tid; l < NB2; l += 256) curp[l] = hist2d[l * NBLK + blk];
    __syncthreads();
    int e0 = blk * CHUNK;
    for (int i = tid; i < CHUNK; i += 256) {
        int r = ei[e0 + i];
        int c = ei[EDGES + e0 + i];
        int b = c >> 9;
        int p = atomicAdd(&curp[b], 1);
        if (p < CAPB) bdata[(size_t)b * CAPB + p] = (r << 9) | (c & 511);
    }
}

// ---- per-bucket LDS counting sort (512 threads) + fused dinv + x pre-scale ----
__global__ void __launch_bounds__(512)
k_csrsort(const int* __restrict__ bcnt, const int* __restrict__ bdata,
          int* __restrict__ rows, int* __restrict__ offp, float* __restrict__ dinv,
          const float* __restrict__ x, __half2* __restrict__ xsH) {
    __shared__ int sidx[CAPB];          // 18.4 KB
    __shared__ int sorted[CAPB];        // 18.4 KB
    __shared__ int hist[NW], curp[NW], ssc[NW];
    __shared__ float sdinv[NW];
    int b = blockIdx.x, tid = threadIdx.x;
    int total = bcnt[b]; if (total > CAPB) total = CAPB;
    hist[tid] = 0;
    __syncthreads();
    const int* base = bdata + (size_t)b * CAPB;
    for (int i = tid; i < total; i += 512) {
        int w = base[i];
        sidx[i] = w;
        atomicAdd(&hist[w & 511], 1);
    }
    __syncthreads();
    int v = hist[tid];
    ssc[tid] = v;
    __syncthreads();
    for (int st = 1; st < NW; st <<= 1) {
        int t = (tid >= st) ? ssc[tid - st] : 0;
        __syncthreads();
        ssc[tid] += t;
        __syncthreads();
    }
    float dval = rsqrtf((float)v + 1.0f);
    curp[tid] = ssc[tid] - v;                       // exclusive start
    offp[b * NW + tid] = ssc[tid];                  // inclusive end
    dinv[b * NW + tid] = dval;                      // degree byproduct
    sdinv[tid] = dval;
    __syncthreads();
    for (int i = tid; i < total; i += 512) {
        int w = sidx[i];
        int pos = atomicAdd(&curp[w & 511], 1);
        sorted[pos] = w >> 9;
    }
    // fused pre-scale for this bucket's 512 nodes
    for (int i = tid; i < NW * 8; i += 512) {
        int nl = i >> 3;
        float d = sdinv[nl];
        float2 xv = ((const float2*)x)[(size_t)(b * NW) * 8 + i];
        xsH[(size_t)(b * NW) * 8 + i] = __floats2half2_rn(xv.x * d, xv.y * d);
    }
    __syncthreads();
    for (int i = tid; i < total; i += 512) rows[(size_t)b * CAPB + i] = sorted[i];
}

// ---- Wih f32 -> f16 ----
__global__ void k_wihcvt(const float* __restrict__ Wih, __half2* __restrict__ WihH) {
    int i = blockIdx.x * blockDim.x + threadIdx.x;   // 65536 float4 lanes
    if (i >= 128 * ROWD / 4) return;
    float4 v = ((const float4*)Wih)[i];
    WihH[i * 2 + 0] = __floats2half2_rn(v.x, v.y);
    WihH[i * 2 + 1] = __floats2half2_rn(v.z, v.w);
}

// ---- zero-atomic CSR gather-reduce, f32 accumulate, fused self (+b2,relu L2) ----
template<int LAYER>
__global__ void __launch_bounds__(256)
k_aggcsr(const int* __restrict__ rows, const int* __restrict__ off,
         const float* __restrict__ dinv, const __half2* __restrict__ srcH,
         const float* __restrict__ b2, __half2* __restrict__ outH) {
    int i = blockIdx.x * blockDim.x + threadIdx.x;
    if (i >= NN * 8) return;
    int n = i >> 3, f2 = i & 7;
    int begin = (n & 511) ? off[n - 1] : 0;
    int end = off[n];
    const size_t base = (size_t)(n >> 9) * CAPB;
    float2 selfv = __half22float2(srcH[(size_t)n * 8 + f2]);
    float ax = selfv.x, ay = selfv.y;
    for (size_t e = base + begin; e < base + end; ++e) {
        int r = rows[e];
        float2 v = __half22float2(srcH[(size_t)r * 8 + f2]);
        ax += v.x; ay += v.y;
    }
    float d = dinv[n];
    ax *= d; ay *= d;
    if (LAYER == 2) {
        ax = fmaxf(ax + b2[f2 * 2 + 0], 0.f);
        ay = fmaxf(ay + b2[f2 * 2 + 1], 0.f);
    }
    outH[i] = __floats2half2_rn(ax, ay);
}

// ---- fused MLP: hid = relu(in1@W1+b1) ; t2s = (hid@W2)*dinv -> fp16 over xsH ----
__global__ void k_gcnmlp(const __half2* __restrict__ in1H, __half2* __restrict__ xsH,
                         const float* __restrict__ dinv,
                         const float* __restrict__ W1, const float* __restrict__ b1,
                         const float* __restrict__ W2) {
    __shared__ float sW1[FEATD * HIDD];
    __shared__ float sW2[HIDD * FEATD];
    __shared__ float sb1[HIDD];
    for (int l = threadIdx.x; l < FEATD * HIDD; l += blockDim.x) {
        sW1[l] = W1[l];
        sW2[l] = W2[l];
    }
    if (threadIdx.x < HIDD) sb1[threadIdx.x] = b1[threadIdx.x];
    __syncthreads();
    int n = blockIdx.x * blockDim.x + threadIdx.x;
    if (n >= NN) return;
    union { float4 f4; __half2 h2[4]; } a0, a1;
    a0.f4 = ((const float4*)(in1H + (size_t)n * 8))[0];
    a1.f4 = ((const float4*)(in1H + (size_t)n * 8))[1];
    float in[FEATD];
#pragma unroll
    for (int q = 0; q < 4; q++) {
        float2 v = __half22float2(a0.h2[q]);
        in[q * 2 + 0] = v.x; in[q * 2 + 1] = v.y;
        v = __half22float2(a1.h2[q]);
        in[8 + q * 2 + 0] = v.x; in[8 + q * 2 + 1] = v.y;
    }
    float out[FEATD];
#pragma unroll
    for (int c = 0; c < FEATD; c++) out[c] = 0.f;
#pragma unroll 8
    for (int j = 0; j < HIDD; j++) {
        float h = sb1[j];
#pragma unroll
        for (int f = 0; f < FEATD; f++) h += in[f] * sW1[f * HIDD + j];
        h = fmaxf(h, 0.f);
#pragma unroll
        for (int c = 0; c < FEATD; c++) out[c] += h * sW2[j * FEATD + c];
    }
    float dn = dinv[n];
    union { float4 f4; __half2 h2[4]; } o0, o1;
#pragma unroll
    for (int q = 0; q < 4; q++) {
        o0.h2[q] = __floats2half2_rn(out[q * 2] * dn, out[q * 2 + 1] * dn);
        o1.h2[q] = __floats2half2_rn(out[8 + q * 2] * dn, out[8 + q * 2 + 1] * dn);
    }
    ((float4*)(xsH + (size_t)n * 8))[0] = o0.f4;
    ((float4*)(xsH + (size_t)n * 8))[1] = o1.f4;
}

// ---- LSTM input GEMM via MFMA 16x16x16 f16 ----
// grid (64, 16); block 256 = 4 waves; block tile 32 rows x 128 cols, K-span 128.
// Wave w: row-tile rt=w&1, col-half ch=w>>1 (4 x 16x16 tiles).
// B panel (WihH[j][k0..k0+127]) staged in LDS [j][k] (pad 8) -> b-frag = ds_read_b64.
__global__ void __launch_bounds__(256)
k_gemmA(const __half* __restrict__ h2, const __half* __restrict__ WihH,
        float* __restrict__ gxp) {
    __shared__ __half Bs[128][KSPAN + 8];   // 34.8 KB, 16B-aligned rows (272 B)
    int tid = threadIdx.x;
    int row0 = blockIdx.x * 32;
    int k0 = blockIdx.y * KSPAN;
    for (int idx = tid; idx < 128 * (KSPAN / 8); idx += 256) {   // 128 x 16 chunks of 8 halfs
        int j = idx >> 4, c8 = (idx & 15) * 8;
        *(float4*)&Bs[j][c8] = *(const float4*)&WihH[(size_t)j * ROWD + k0 + c8];
    }
    __syncthreads();
    int w = tid >> 6;
    int l = tid & 63;
    int rt = w & 1;            // row tile (16 rows)
    int ch = w >> 1;           // col half (64 cols)
    int m = l & 15;
    int kg = l >> 4;
    float4v acc0 = {0.f, 0.f, 0.f, 0.f};
    float4v acc1 = {0.f, 0.f, 0.f, 0.f};
    float4v acc2 = {0.f, 0.f, 0.f, 0.f};
    float4v acc3 = {0.f, 0.f, 0.f, 0.f};
    const __half* aptr = h2 + (size_t)(row0 + rt * 16 + m) * ROWD + k0 + kg * 4;
#pragma unroll
    for (int kk = 0; kk < KSPAN; kk += 16) {
        half4v a = *(const half4v*)(aptr + kk);
        half4v b0 = *(const half4v*)&Bs[ch * 64 + 0 * 16 + m][kk + kg * 4];
        half4v b1 = *(const half4v*)&Bs[ch * 64 + 1 * 16 + m][kk + kg * 4];
        half4v b2 = *(const half4v*)&Bs[ch * 64 + 2 * 16 + m][kk + kg * 4];
        half4v b3 = *(const half4v*)&Bs[ch * 64 + 3 * 16 + m][kk + kg * 4];
        acc0 = __builtin_amdgcn_mfma_f32_16x16x16f16(a, b0, acc0, 0, 0, 0);
        acc1 = __builtin_amdgcn_mfma_f32_16x16x16f16(a, b1, acc1, 0, 0, 0);
        acc2 = __builtin_amdgcn_mfma_f32_16x16x16f16(a, b2, acc2, 0, 0, 0);
        acc3 = __builtin_amdgcn_mfma_f32_16x16x16f16(a, b3, acc3, 0, 0, 0);
    }
    // D layout (verified): col = l&15, row = (l>>4)*4 + reg
    float* ob = gxp + (size_t)blockIdx.y * (ROWD * 128) + (size_t)(row0 + rt * 16) * 128 + ch * 64;
#pragma unroll
    for (int i = 0; i < 4; i++) {
        size_t ro = (size_t)(kg * 4 + i) * 128;
        ob[ro + 0 * 16 + m] = acc0[i];
        ob[ro + 1 * 16 + m] = acc1[i];
        ob[ro + 2 * 16 + m] = acc2[i];
        ob[ro + 3 * 16 + m] = acc3[i];
    }
}

// ---- gxp partial-sum prereduce ----
__global__ void k_pre(const float* __restrict__ gxp, float* __restrict__ sgx) {
    int i = blockIdx.x * blockDim.x + threadIdx.x;   // ROWD*128 lanes
    if (i >= ROWD * 128) return;
    float s = 0.f;
#pragma unroll
    for (int p = 0; p < KCHUNKS; p++) s += gxp[(size_t)p * ROWD * 128 + i];
    sgx[i] = s;
}

// ---- LSTM recurrence (reads pre-summed sgx) ----
__global__ void k_lstm(const float* __restrict__ sgx, const float* __restrict__ Whh,
                       const float* __restrict__ bih, const float* __restrict__ bhh,
                       float* __restrict__ hseq) {
    __shared__ float sWhhT[LSTMH][4 * LSTMH];   // [k][j] = Whh[j][k]
    __shared__ float sgxL[WIN * 4 * LSTMH];      // 16 KB
    __shared__ float sh[LSTMH], sc[LSTMH], sg[4 * LSTMH];
    int b = blockIdx.x, j = threadIdx.x;
    for (int l = j; l < 4 * LSTMH * LSTMH; l += 4 * LSTMH) {
        int r = l >> 5, k = l & 31;
        sWhhT[k][r] = Whh[l];
    }
    for (int l = j; l < WIN * 128; l += 128) sgxL[l] = sgx[(size_t)b * WIN * 128 + l];
    float bias = bih[j] + bhh[j];
    if (j < LSTMH) { sh[j] = 0.f; sc[j] = 0.f; }
    __syncthreads();
    for (int t = 0; t < WIN; t++) {
        float g = bias + sgxL[t * 128 + j];
#pragma unroll
        for (int k = 0; k < LSTMH; k++) g += sWhhT[k][j] * sh[k];
        sg[j] = g;
        __syncthreads();
        if (j < LSTMH) {
            float ig = sg[j], fg = sg[32 + j], gg = sg[64 + j], og = sg[96 + j];
            float c = sc[j];
            float si = 1.f / (1.f + __expf(-ig));
            float sf = 1.f / (1.f + __expf(-fg));
            float so = 1.f / (1.f + __expf(-og));
            c = sf * c + si * tanhf(gg);
            float h = so * tanhf(c);
            sc[j] = c; sh[j] = h;
            if (t >= WIN - WOUT)
                hseq[(size_t)(b * WOUT + (t - (WIN - WOUT))) * LSTMH + j] = h;
        }
        __syncthreads();
    }
}

// ---- FC head: (512 rows) 32 -> 16 relu -> 10 ----
__global__ void k_fc(const float* __restrict__ hseq, const float* __restrict__ Wfc1,
                     const float* __restrict__ bfc1, const float* __restrict__ Wfc2,
                     const float* __restrict__ bfc2, float* __restrict__ out) {
    __shared__ float sW1[16 * 32], sb1[16], sW2[10 * 16], sb2[10];
    int tid = threadIdx.x;
    for (int l = tid; l < 16 * 32; l += blockDim.x) sW1[l] = Wfc1[l];
    if (tid < 16) sb1[tid] = bfc1[tid];
    for (int l = tid; l < 160; l += blockDim.x) sW2[l] = Wfc2[l];
    if (tid < 10) sb2[tid] = bfc2[tid];
    __syncthreads();
    int r = blockIdx.x * blockDim.x + tid;
    if (r >= BATCH * WOUT) return;
    float h[32];
#pragma unroll
    for (int k = 0; k < 32; k++) h[k] = hseq[(size_t)r * 32 + k];
    float hid[16];
#pragma unroll
    for (int j = 0; j < 16; j++) {
        float v = sb1[j];
#pragma unroll
        for (int k = 0; k < 32; k++) v += sW1[j * 32 + k] * h[k];
        hid[j] = fmaxf(v, 0.f);
    }
#pragma unroll
    for (int c = 0; c < NCLS; c++) {
        float v = sb2[c];
#pragma unroll
        for (int j = 0; j < 16; j++) v += sW2[c * 16 + j] * hid[j];
        out[(size_t)r * NCLS + c] = v;
    }
}

extern "C" void kernel_launch(void* const* d_in, const int* in_sizes, int n_in,
                              void* d_out, int out_size, void* d_ws, size_t ws_size,
                              hipStream_t stream) {
    const float* x    = (const float*)d_in[0];
    const int*   ei   = (const int*)d_in[1];
    const float* W1   = (const float*)d_in[2];
    const float* b1   = (const float*)d_in[3];
    const float* W2   = (const float*)d_in[4];
    const float* b2   = (const float*)d_in[5];
    const float* Wih  = (const float*)d_in[6];
    const float* Whh  = (const float*)d_in[7];
    const float* bih  = (const float*)d_in[8];
    const float* bhh  = (const float*)d_in[9];
    const float* Wfc1 = (const float*)d_in[10];
    const float* bfc1 = (const float*)d_in[11];
    const float* Wfc2 = (const float*)d_in[12];
    const float* bfc2 = (const float*)d_in[13];
    float* out = (float*)d_out;

    float*   ws     = (float*)d_ws;
    float*   dinv   = ws;                                    // NN f32 (1 MB)
    int*     hist2d = (int*)(dinv + NN);                     // NB2*NBLK ints (0.5 MB)
    int*     bcnt   = hist2d + NB2 * NBLK;                   // NB2 ints
    int*     off    = bcnt + NB2;                            // NN ints (1 MB)
    int*     rows   = off + NN;                              // NB2*CAPB ints (9.4 MB)
    __half2* aggH   = (__half2*)(rows + (size_t)NB2 * CAPB); // NN*8 half2 (8 MB)
    __half2* xsH    = aggH + (size_t)NN * 8;                 // NN*8 half2 (8 MB)
    int*     bdata  = (int*)(xsH + (size_t)NN * 8);          // NB2*CAPB ints (9.4 MB)
    float*   gxp    = (float*)(bdata + (size_t)NB2 * CAPB);  // KCHUNKS*2048*128 f32 (16 MB)
    float*   sgx    = gxp + (size_t)KCHUNKS * ROWD * 128;    // 1 MB
    float*   hseq   = sgx + ROWD * 128;                      // 64 KB
    __half2* WihH   = (__half2*)(hseq + BATCH * WOUT * LSTMH); // 0.5 MB

    k_hist<<<NBLK, 256, 0, stream>>>(ei, hist2d);
    k_scan2<<<NB2, NBLK, 0, stream>>>(hist2d, bcnt);
    k_place<<<NBLK, 256, 0, stream>>>(ei, hist2d, bdata);
    k_csrsort<<<NB2, 512, 0, stream>>>(bcnt, bdata, rows, off, dinv, x, xsH);
    k_wihcvt<<<128 * ROWD / 4 / 256, 256, 0, stream>>>(Wih, WihH);

    k_aggcsr<1><<<NN * 8 / 256, 256, 0, stream>>>(rows, off, dinv, xsH, b2, aggH);  // in1
    k_gcnmlp<<<NN / 256, 256, 0, stream>>>(aggH, xsH, dinv, W1, b1, W2);            // t2s
    k_aggcsr<2><<<NN * 8 / 256, 256, 0, stream>>>(rows, off, dinv, xsH, b2, aggH);  // h2

    dim3 gg(ROWD / 32, KCHUNKS);
    k_gemmA<<<gg, 256, 0, stream>>>((const __half*)aggH, (const __half*)WihH, gxp);
    k_pre<<<ROWD * 128 / 256, 256, 0, stream>>>(gxp, sgx);
    k_lstm<<<BATCH, 128, 0, stream>>>(sgx, Whh, bih, bhh, hseq);
    k_fc<<<2, 256, 0, stream>>>(hseq, Wfc1, bfc1, Wfc2, bfc2, out);
}